// Round 13
// baseline (482.019 us; speedup 1.0000x reference)
//
#include <hip/hip_runtime.h>

// ---------------- problem constants ----------------
constexpr int N_NODES = 30000;
constexpr int N_EDGES = 300000;
constexpr int GRAPHS  = 64;
constexpr int F_IN    = 33;
constexpr int HID     = 132;
constexpr int HID4    = 528;
constexpr int OUT_DIM = 128;
constexpr int GFC     = 1024;
constexpr int MP      = 30016;
constexpr int NBLK    = 118;           // ceil(N_NODES/256)
constexpr int YW      = 544;           // y row stride u16

typedef unsigned int u32;
typedef unsigned short u16;

// ---------------- workspace layout ----------------
constexpr size_t rnd64(size_t x) { return (x + 63) & ~(size_t)63; }
constexpr size_t O_DIS   = 0;
constexpr size_t O_CNT   = O_DIS   + rnd64(N_NODES);
constexpr size_t O_WDEG  = O_CNT   + rnd64(N_NODES);
constexpr size_t O_IDP   = O_WDEG  + rnd64(N_NODES);
constexpr size_t O_BSUM  = O_IDP   + rnd64(N_NODES + 1);
constexpr size_t O_CSR_S = O_BSUM  + rnd64(128);
constexpr size_t O_CSR_W = O_CSR_S + rnd64(N_EDGES);
constexpr size_t O_ESD   = O_CSR_W + rnd64(N_EDGES);                 // float, N*8
constexpr size_t O_GE    = O_ESD   + rnd64((size_t)N_NODES * 8);     // u32, G*HID
constexpr size_t O_CMP1  = O_GE    + rnd64(GRAPHS * HID);            // float, 8*132
constexpr size_t O_CMP2  = O_CMP1  + rnd64(8 * HID);
// u16 region
constexpr size_t O_U     = O_CMP2  + rnd64(8 * HID);
constexpr size_t U_ABX   = 0;                                        // [MP,64] X bf16
constexpr size_t U_AGG   = U_ABX  + rnd64((size_t)MP * 64);          // [MP,64] aggX
constexpr size_t U_Y     = U_AGG  + rnd64((size_t)MP * 64);          // [MP,YW]
constexpr size_t U_ABF   = U_Y    + rnd64((size_t)MP * YW);          // [MP,160] x table
constexpr size_t U_ABG   = U_ABF  + rnd64((size_t)MP * 160);         // [MP,288]
constexpr size_t U_BTG   = U_ABG  + rnd64((size_t)MP * 288);         // [192,288]
constexpr size_t U_BTGCN = U_BTG  + rnd64(192 * 288);                // [192,64]
constexpr size_t U_BTY1  = U_BTGCN+ rnd64(192 * 64);                 // [192,544]
constexpr size_t U_BTY2  = U_BTY1 + rnd64(192 * 544);                // [192,544]
constexpr size_t U_BTS1  = U_BTY2 + rnd64(192 * 544);                // [1024,160]
constexpr size_t U_BTS2  = U_BTS1 + rnd64(1024 * 160);               // [128,1024]

// ---------------- bf16 helpers ----------------
__device__ inline u16 f2bf(float f) {
    u32 u = __float_as_uint(f);
    return (u16)((u + 0x7fffu + ((u >> 16) & 1u)) >> 16);
}
__device__ inline u32 pk2(float a, float b) { return (u32)f2bf(a) | ((u32)f2bf(b) << 16); }
__device__ inline float bflo(u32 w) { return __uint_as_float(w << 16); }
__device__ inline float bfhi(u32 w) { return __uint_as_float(w & 0xffff0000u); }
__device__ inline float bf1(u16 x) { return __uint_as_float((u32)x << 16); }
__device__ inline u32 encf(float x) {
    u32 u = __float_as_uint(x);
    return (u & 0x80000000u) ? ~u : (u | 0x80000000u);
}
__device__ inline float decf(u32 e) {
    u32 u = (e & 0x80000000u) ? (e & 0x7fffffffu) : ~e;
    return __uint_as_float(u);
}
__device__ inline float lrelu(float x) { return (x >= 0.f) ? x : 0.2f * x; }

typedef __attribute__((ext_vector_type(8))) short s8b;
typedef __attribute__((ext_vector_type(4))) float f32x4;

// ---------------- CSR build ----------------
__global__ void k_count(const int* __restrict__ ei, const float* __restrict__ ew,
                        int* __restrict__ counts, float* __restrict__ wdeg) {
    int e = blockIdx.x * 256 + threadIdx.x;
    if (e < N_EDGES) {
        int dst = ei[N_EDGES + e];
        atomicAdd(&counts[dst], 1);
        atomicAdd(&wdeg[dst], ew[e]);
    }
}

__global__ __launch_bounds__(256) void k_bsum(const int* __restrict__ counts,
                                              const float* __restrict__ wdeg,
                                              int* __restrict__ bsum,
                                              float* __restrict__ dis) {
    int i = blockIdx.x * 256 + threadIdx.x;
    int v = (i < N_NODES) ? counts[i] : 0;
    if (i < N_NODES) {
        float d = 1.f + wdeg[i];
        dis[i] = (d > 0.f) ? rsqrtf(fmaxf(d, 1e-12f)) : 0.f;
    }
    int x = v;
    #pragma unroll
    for (int off = 1; off < 64; off <<= 1) x += __shfl_xor(x, off);
    __shared__ int ws4[4];
    if ((threadIdx.x & 63) == 0) ws4[threadIdx.x >> 6] = x;
    __syncthreads();
    if (threadIdx.x == 0) bsum[blockIdx.x] = ws4[0] + ws4[1] + ws4[2] + ws4[3];
}

__global__ __launch_bounds__(256) void k_apply(int* __restrict__ counts,
                                               const int* __restrict__ bsum,
                                               int* __restrict__ indptr) {
    __shared__ int s1[4], s2[4];
    const int b = blockIdx.x;
    const int tid = threadIdx.x, lane = tid & 63, w = tid >> 6;
    int part = (tid < b) ? bsum[tid] : 0;
    #pragma unroll
    for (int off = 1; off < 64; off <<= 1) part += __shfl_xor(part, off);
    if (lane == 0) s1[w] = part;
    int i = b * 256 + tid;
    int v = (i < N_NODES) ? counts[i] : 0;
    int x = v;
    #pragma unroll
    for (int off = 1; off < 64; off <<= 1) {
        int y = __shfl_up(x, off);
        if (lane >= off) x += y;
    }
    if (lane == 63) s2[w] = x;
    __syncthreads();
    int add = s1[0] + s1[1] + s1[2] + s1[3];
    for (int k2 = 0; k2 < w; ++k2) add += s2[k2];
    if (i < N_NODES) {
        indptr[i] = add + x - v;
        counts[i] = 0;
    }
    if (i == N_NODES) indptr[N_NODES] = N_EDGES;
}

__global__ void k_scatter(const int* __restrict__ ei, const float* __restrict__ ew,
                          const int* __restrict__ indptr, int* __restrict__ cursor,
                          int* __restrict__ csr_src, float* __restrict__ csr_w) {
    int e = blockIdx.x * 256 + threadIdx.x;
    if (e >= N_EDGES) return;
    int src = ei[e];
    int dst = ei[N_EDGES + e];
    int pos = indptr[dst] + atomicAdd(&cursor[dst], 1);
    csr_src[pos] = src;
    csr_w[pos] = ew[e];
}

// ---------------- merged weight + X conversion + zeroing ----------------
constexpr int S0 = 192 * 288;
constexpr int S1 = 192 * 64;
constexpr int S2 = 192 * 544;
constexpr int S3 = 192 * 544;
constexpr int S4 = 1024 * 160;
constexpr int S5 = 128 * 1024;
constexpr int S6 = N_NODES * 64;
constexpr int S7 = 2 * 8 * HID;
constexpr int S8 = N_NODES + N_NODES + GRAPHS * HID;
constexpr int SW_TOT = S0 + S1 + S2 + S3 + S4 + S5 + S6 + S7 + S8;

__global__ void k_cvtW(const float* __restrict__ Wfc1, const float* __restrict__ Wfc2,
                       const float* __restrict__ Wgcn, const float* __restrict__ Wgat1,
                       const float* __restrict__ Wgat2, const float* __restrict__ Wg1,
                       const float* __restrict__ Wg2, const float* __restrict__ X,
                       const float* __restrict__ as1, const float* __restrict__ ad1,
                       const float* __restrict__ as2, const float* __restrict__ ad2,
                       u16* __restrict__ BTG, u16* __restrict__ BTGCN,
                       u16* __restrict__ BTY1, u16* __restrict__ BTY2,
                       u16* __restrict__ BTS1, u16* __restrict__ BTS2,
                       float* __restrict__ cmp1, float* __restrict__ cmp2,
                       u16* __restrict__ ABX,
                       u32* __restrict__ zc, u32* __restrict__ zw, u32* __restrict__ zg) {
    int idx = blockIdx.x * 256 + threadIdx.x;
    if (idx < S0) {
        int n = idx / 288, k = idx - n * 288;
        u16 v = 0;
        if (n < HID) {
            if (k < HID) v = f2bf(Wfc1[(size_t)k * HID + n]);
            else if (k < 2 * HID) v = f2bf(Wfc2[(size_t)(k - HID) * HID + n]);
        }
        BTG[idx] = v;
        return;
    }
    idx -= S0;
    if (idx < S1) {
        int n = idx / 64, k = idx - n * 64;
        BTGCN[idx] = (k < F_IN && n < HID) ? f2bf(Wgcn[(size_t)k * HID + n]) : (u16)0;
        return;
    }
    idx -= S1;
    if (idx < S2 + S3) {
        int l = (idx >= S2);
        int li = l ? (idx - S2) : idx;
        int n = li / 544, c = li - n * 544;
        int k = c / 136, j = c - k * 136;
        const float* W = l ? Wgat2 : Wgat1;
        u16 v = 0;
        if (n < HID && j < HID) v = f2bf(0.25f * W[(size_t)j * HID4 + k * HID + n]);
        (l ? BTY2 : BTY1)[li] = v;
        return;
    }
    idx -= S2 + S3;
    if (idx < S4) {
        int n = idx / 160, k = idx - n * 160;
        BTS1[idx] = (k < HID) ? f2bf(Wg1[(size_t)k * GFC + n]) : (u16)0;
        return;
    }
    idx -= S4;
    if (idx < S5) {
        int n = idx / 1024, k = idx - n * 1024;
        BTS2[idx] = f2bf(Wg2[(size_t)k * OUT_DIM + n]);
        return;
    }
    idx -= S5;
    if (idx < S6) {
        int r = idx / 64, k = idx - r * 64;
        ABX[idx] = (k < F_IN) ? f2bf(X[(size_t)r * F_IN + k]) : (u16)0;
        return;
    }
    idx -= S6;
    if (idx < S7) {
        int l = idx / (8 * HID); idx -= l * (8 * HID);
        int q = idx / HID;  int c = idx - q * HID;
        int k = q & 3;
        const float* W = l ? Wgat2 : Wgat1;
        const float* a = (q < 4) ? (l ? as2 : as1) : (l ? ad2 : ad1);
        const float* wr = W + (size_t)c * HID4 + k * HID;
        const float* ar = a + k * HID;
        float sum = 0.f;
        for (int cc = 0; cc < HID; ++cc) sum += wr[cc] * ar[cc];
        (l ? cmp2 : cmp1)[q * HID + c] = sum;
        return;
    }
    idx -= S7;
    if (idx < S8) {
        if (idx < N_NODES) zc[idx] = 0;
        else if (idx < 2 * N_NODES) zw[idx - N_NODES] = 0;
        else zg[idx - 2 * N_NODES] = 0;
    }
}

// ---------------- MFMA bf16 GEMM, NT column-tiles, optional fused esd --------
template <int NT, bool ESD>
__global__ __launch_bounds__(256) void k_gemm(
    const u16* __restrict__ A, const u16* __restrict__ Bt,
    int M, int N, int Kp,
    float* __restrict__ Cf,
    u16* __restrict__ Cb, int ldcb, int padN,
    u16* __restrict__ Cb2, int ldcb2, int coff2,
    const float* __restrict__ bias, int relu, int gate,
    const float* __restrict__ b2, const float* __restrict__ pb,
    u32* __restrict__ genc,
    const float* __restrict__ compG, float* __restrict__ esdOut) {
    __shared__ float xs[ESD ? 64 : 1][134];
    __shared__ float cmp[ESD ? 8 : 1][132];
    const int bm = blockIdx.x * 64;
    const int w = threadIdx.x >> 6;
    const int lane = threadIdx.x & 63;
    const int m16 = lane & 15;
    const int quad = lane >> 4;
    const u16* Ab = A + (size_t)(bm + m16) * Kp + quad * 8;
    const u16* Bb[NT];
    #pragma unroll
    for (int j = 0; j < NT; ++j)
        Bb[j] = Bt + (size_t)(j * 64 + w * 16 + m16) * Kp + quad * 8;
    f32x4 acc[NT][4];
    #pragma unroll
    for (int j = 0; j < NT; ++j)
        #pragma unroll
        for (int r = 0; r < 4; ++r) acc[j][r] = (f32x4){0.f, 0.f, 0.f, 0.f};
    for (int k0 = 0; k0 < Kp; k0 += 32) {
        s8b a0 = *(const s8b*)(Ab + k0);
        s8b a1 = *(const s8b*)(Ab + (size_t)16 * Kp + k0);
        s8b a2 = *(const s8b*)(Ab + (size_t)32 * Kp + k0);
        s8b a3 = *(const s8b*)(Ab + (size_t)48 * Kp + k0);
        #pragma unroll
        for (int j = 0; j < NT; ++j) {
            s8b b = *(const s8b*)(Bb[j] + k0);
            acc[j][0] = __builtin_amdgcn_mfma_f32_16x16x32_bf16(a0, b, acc[j][0], 0, 0, 0);
            acc[j][1] = __builtin_amdgcn_mfma_f32_16x16x32_bf16(a1, b, acc[j][1], 0, 0, 0);
            acc[j][2] = __builtin_amdgcn_mfma_f32_16x16x32_bf16(a2, b, acc[j][2], 0, 0, 0);
            acc[j][3] = __builtin_amdgcn_mfma_f32_16x16x32_bf16(a3, b, acc[j][3], 0, 0, 0);
        }
    }
    const int g0 = (bm * GRAPHS) / N_NODES;
    int gend = bm + 63; if (gend >= M) gend = M - 1;
    const int g1 = (gend * GRAPHS) / N_NODES;
    #pragma unroll
    for (int j = 0; j < NT; ++j) {
        const int col = j * 64 + w * 16 + m16;
        const bool colok = col < N;
        float bsum = 0.f;
        if (colok) {
            if (gate) bsum = bias[col] + b2[col] + pb[col];
            else if (bias) bsum = bias[col];
        }
        float mx0 = -3.4e38f, mx1 = -3.4e38f;
        #pragma unroll
        for (int r = 0; r < 4; ++r) {
            #pragma unroll
            for (int jj = 0; jj < 4; ++jj) {
                int row = bm + r * 16 + quad * 4 + jj;
                if (row >= M || !colok) continue;
                float v = acc[j][r][jj] + bsum;
                float res;
                if (gate) {
                    float z = 1.f / (1.f + expf(-v));
                    float xcv = bf1(A[(size_t)row * Kp + col]);
                    float xpv = bf1(A[(size_t)row * Kp + 132 + col]);
                    res = z * xcv + (1.f - z) * xpv;
                } else {
                    if (relu) v = fmaxf(v, 0.f);
                    res = v;
                }
                if constexpr (ESD) {
                    if (col < 132) xs[row - bm][col] = res;
                }
                if (genc) {
                    int gid = (row * GRAPHS) / N_NODES;
                    if (gid == g0) mx0 = fmaxf(mx0, res);
                    else           mx1 = fmaxf(mx1, res);
                }
                if (Cf) Cf[(size_t)row * N + col] = res;
                if (Cb) Cb[(size_t)row * ldcb + col] = f2bf(res);
                if (Cb2) Cb2[(size_t)row * ldcb2 + coff2 + col] = f2bf(res);
            }
        }
        if (genc && colok) {
            mx0 = fmaxf(mx0, __shfl_xor(mx0, 16));
            mx0 = fmaxf(mx0, __shfl_xor(mx0, 32));
            if (g1 != g0) {
                mx1 = fmaxf(mx1, __shfl_xor(mx1, 16));
                mx1 = fmaxf(mx1, __shfl_xor(mx1, 32));
            }
            if (quad == 0) {
                atomicMax(&genc[g0 * HID + col], encf(mx0));
                if (g1 != g0) atomicMax(&genc[g1 * HID + col], encf(mx1));
            }
        }
    }
    if constexpr (ESD) {
        for (int i2 = threadIdx.x; i2 < 8 * HID; i2 += 256)
            cmp[i2 / HID][i2 % HID] = compG[i2];
        __syncthreads();
        int row = threadIdx.x >> 2, q = threadIdx.x & 3;
        if (bm + row < M) {
            float s0 = 0.f, s1 = 0.f;
            for (int c = 0; c < HID; ++c) {
                float xv = xs[row][c];
                s0 += xv * cmp[q][c];
                s1 += xv * cmp[q + 4][c];
            }
            esdOut[(size_t)(bm + row) * 8 + q] = s0;
            esdOut[(size_t)(bm + row) * 8 + 4 + q] = s1;
        }
    }
}

// ---------------- GCN aggregate in X-domain (33 ch, 2 edges/wave-iter) -------
__global__ __launch_bounds__(256) void k_gcn_aggX(
    const u16* __restrict__ xb, const int* __restrict__ indptr,
    const int* __restrict__ csr_src, const float* __restrict__ csr_w,
    const float* __restrict__ dis, u16* __restrict__ aggx) {
    const int w = threadIdx.x >> 6, t = threadIdx.x & 63;
    const int i = blockIdx.x * 4 + w;
    const int g = t >> 5;
    const int c = t & 31;
    const float di = dis[i];
    const int s = indptr[i], e = indptr[i + 1];
    const u32* X32 = (const u32*)xb;
    float aLo = 0.f, aHi = 0.f;
    int j = s;
    for (; j + 3 < e; j += 4) {
        int j0 = j + g, j1 = j + 2 + g;
        int s0 = csr_src[j0], s1 = csr_src[j1];
        float n0 = dis[s0] * csr_w[j0] * di;
        float n1 = dis[s1] * csr_w[j1] * di;
        u32 v0 = X32[(size_t)s0 * 32 + c];
        u32 v1 = X32[(size_t)s1 * 32 + c];
        aLo += n0 * bflo(v0) + n1 * bflo(v1);
        aHi += n0 * bfhi(v0) + n1 * bfhi(v1);
    }
    for (; j < e; j += 2) {
        int jj = j + g;
        if (jj < e) {
            int s0 = csr_src[jj];
            float n0 = dis[s0] * csr_w[jj] * di;
            u32 v0 = X32[(size_t)s0 * 32 + c];
            aLo += n0 * bflo(v0);
            aHi += n0 * bfhi(v0);
        }
    }
    aLo += __shfl_xor(aLo, 32);
    aHi += __shfl_xor(aHi, 32);
    if (t < 32) {
        float nself = di * di;
        u32 v = X32[(size_t)i * 32 + t];
        aLo += nself * bflo(v);
        aHi += nself * bfhi(v);
        ((u32*)aggx)[(size_t)i * 32 + t] = pk2(aLo, aHi);
    }
}

// ---------------- GAT single-pass: fused softmax + x-domain aggregate --------
// y[i,k,:] = ( exp(e_self_k)*x_i + sum_j exp(e_jk)*x_srcj ) / denom_k
__global__ __launch_bounds__(256) void k_gat_node(
    const u16* __restrict__ xt, const float* __restrict__ esd,
    const int* __restrict__ indptr, const int* __restrict__ csr_src,
    u16* __restrict__ y) {
    const int w = threadIdx.x >> 6, t = threadIdx.x & 63;
    const int i = blockIdx.x * 4 + w;
    const int s = indptr[i];
    const int e = indptr[i + 1];
    const float4 ESR = *(const float4*)(esd + (size_t)i * 8);
    const float4 EDR = *(const float4*)(esd + (size_t)i * 8 + 4);
    const float ed0 = EDR.x, ed1 = EDR.y, ed2 = EDR.z, ed3 = EDR.w;
    float a0 = expf(lrelu(ESR.x + ed0));
    float a1 = expf(lrelu(ESR.y + ed1));
    float a2 = expf(lrelu(ESR.z + ed2));
    float a3 = expf(lrelu(ESR.w + ed3));
    float d0 = a0, d1 = a1, d2 = a2, d3 = a3;
    const u32* X = (const u32*)xt;   // row stride 80 u32
    float yL0, yH0, yL1, yH1, yL2, yH2, yL3, yH3;
    float zL0 = 0, zH0 = 0, zL1 = 0, zH1 = 0, zL2 = 0, zH2 = 0, zL3 = 0, zH3 = 0;
    {
        u32 v = X[(size_t)i * 80 + t];
        float lo = bflo(v), hi = bfhi(v);
        yL0 = a0 * lo; yH0 = a0 * hi;
        yL1 = a1 * lo; yH1 = a1 * hi;
        yL2 = a2 * lo; yH2 = a2 * hi;
        yL3 = a3 * lo; yH3 = a3 * hi;
        if (t < 2) {
            u32 v2 = X[(size_t)i * 80 + 64 + t];
            float l2 = bflo(v2), h2 = bfhi(v2);
            zL0 = a0 * l2; zH0 = a0 * h2;
            zL1 = a1 * l2; zH1 = a1 * h2;
            zL2 = a2 * l2; zH2 = a2 * h2;
            zL3 = a3 * l2; zH3 = a3 * h2;
        }
    }
    int j = s;
    for (; j + 1 < e; j += 2) {
        int s0 = csr_src[j], s1 = csr_src[j + 1];
        float4 q0 = *(const float4*)(esd + (size_t)s0 * 8);
        float4 q1 = *(const float4*)(esd + (size_t)s1 * 8);
        u32 v0 = X[(size_t)s0 * 80 + t];
        u32 v1 = X[(size_t)s1 * 80 + t];
        float x00 = expf(lrelu(q0.x + ed0));
        float x01 = expf(lrelu(q0.y + ed1));
        float x02 = expf(lrelu(q0.z + ed2));
        float x03 = expf(lrelu(q0.w + ed3));
        float x10 = expf(lrelu(q1.x + ed0));
        float x11 = expf(lrelu(q1.y + ed1));
        float x12 = expf(lrelu(q1.z + ed2));
        float x13 = expf(lrelu(q1.w + ed3));
        d0 += x00 + x10; d1 += x01 + x11; d2 += x02 + x12; d3 += x03 + x13;
        float l0 = bflo(v0), h0 = bfhi(v0), l1 = bflo(v1), h1 = bfhi(v1);
        yL0 += x00 * l0 + x10 * l1; yH0 += x00 * h0 + x10 * h1;
        yL1 += x01 * l0 + x11 * l1; yH1 += x01 * h0 + x11 * h1;
        yL2 += x02 * l0 + x12 * l1; yH2 += x02 * h0 + x12 * h1;
        yL3 += x03 * l0 + x13 * l1; yH3 += x03 * h0 + x13 * h1;
        if (t < 2) {
            u32 u0 = X[(size_t)s0 * 80 + 64 + t];
            u32 u1 = X[(size_t)s1 * 80 + 64 + t];
            float el0 = bflo(u0), eh0 = bfhi(u0), el1 = bflo(u1), eh1 = bfhi(u1);
            zL0 += x00 * el0 + x10 * el1; zH0 += x00 * eh0 + x10 * eh1;
            zL1 += x01 * el0 + x11 * el1; zH1 += x01 * eh0 + x11 * eh1;
            zL2 += x02 * el0 + x12 * el1; zH2 += x02 * eh0 + x12 * eh1;
            zL3 += x03 * el0 + x13 * el1; zH3 += x03 * eh0 + x13 * eh1;
        }
    }
    if (j < e) {
        int s0 = csr_src[j];
        float4 q0 = *(const float4*)(esd + (size_t)s0 * 8);
        u32 v0 = X[(size_t)s0 * 80 + t];
        float x00 = expf(lrelu(q0.x + ed0));
        float x01 = expf(lrelu(q0.y + ed1));
        float x02 = expf(lrelu(q0.z + ed2));
        float x03 = expf(lrelu(q0.w + ed3));
        d0 += x00; d1 += x01; d2 += x02; d3 += x03;
        float l0 = bflo(v0), h0 = bfhi(v0);
        yL0 += x00 * l0; yH0 += x00 * h0;
        yL1 += x01 * l0; yH1 += x01 * h0;
        yL2 += x02 * l0; yH2 += x02 * h0;
        yL3 += x03 * l0; yH3 += x03 * h0;
        if (t < 2) {
            u32 u0 = X[(size_t)s0 * 80 + 64 + t];
            float el0 = bflo(u0), eh0 = bfhi(u0);
            zL0 += x00 * el0; zH0 += x00 * eh0;
            zL1 += x01 * el0; zH1 += x01 * eh0;
            zL2 += x02 * el0; zH2 += x02 * eh0;
            zL3 += x03 * el0; zH3 += x03 * eh0;
        }
    }
    float i0 = 1.f / d0, i1 = 1.f / d1, i2 = 1.f / d2, i3 = 1.f / d3;
    u32* yr = (u32*)(y + (size_t)i * YW);
    yr[t]       = pk2(yL0 * i0, yH0 * i0);
    yr[68 + t]  = pk2(yL1 * i1, yH1 * i1);
    yr[136 + t] = pk2(yL2 * i2, yH2 * i2);
    yr[204 + t] = pk2(yL3 * i3, yH3 * i3);
    if (t < 2) {
        yr[64 + t]  = pk2(zL0 * i0, zH0 * i0);
        yr[132 + t] = pk2(zL1 * i1, zH1 * i1);
        yr[200 + t] = pk2(zL2 * i2, zH2 * i2);
        yr[268 + t] = pk2(zL3 * i3, zH3 * i3);
    } else if (t < 4) {
        yr[64 + t] = 0; yr[132 + t] = 0; yr[200 + t] = 0; yr[268 + t] = 0;
    }
}

// ---------------- MLP head ----------------
__global__ __launch_bounds__(256) void k_head(
    const u32* __restrict__ genc, const u16* __restrict__ BTS1,
    const u16* __restrict__ BTS2, const float* __restrict__ b_g1,
    const float* __restrict__ b_g2, float* __restrict__ out) {
    __shared__ u32 g_sm[66];
    __shared__ float h_sm[GFC];
    __shared__ float part[OUT_DIM];
    const int g = blockIdx.x;
    const int tid = threadIdx.x;
    if (tid < 66) {
        float a0 = decf(genc[g * HID + 2 * tid]);
        float a1 = decf(genc[g * HID + 2 * tid + 1]);
        g_sm[tid] = pk2(a0, a1);
    }
    __syncthreads();
    #pragma unroll
    for (int r = 0; r < 4; ++r) {
        int o = tid + 256 * r;
        const u32* wr = (const u32*)(BTS1 + (size_t)o * 160);
        float acc = 0.f;
        for (int c = 0; c < 66; ++c) {
            u32 wv = wr[c], gv = g_sm[c];
            acc += bflo(wv) * bflo(gv) + bfhi(wv) * bfhi(gv);
        }
        acc = fmaxf(acc + b_g1[o], 0.f);
        h_sm[o] = __uint_as_float((u32)f2bf(acc) << 16);
    }
    __syncthreads();
    const int o = tid & 127, half = tid >> 7;
    const u32* wr2 = (const u32*)(BTS2 + (size_t)o * 1024 + half * 512);
    const float* hh = h_sm + half * 512;
    float acc = 0.f;
    for (int c = 0; c < 256; ++c) {
        u32 wv = wr2[c];
        acc += bflo(wv) * hh[2 * c] + bfhi(wv) * hh[2 * c + 1];
    }
    if (half == 1) part[o] = acc;
    __syncthreads();
    if (half == 0) out[(size_t)g * OUT_DIM + o] = acc + part[o] + b_g2[o];
}

// ---------------- launch ----------------
extern "C" void kernel_launch(void* const* d_in, const int* in_sizes, int n_in,
                              void* d_out, int out_size, void* d_ws, size_t ws_size,
                              hipStream_t stream) {
    const float* X       = (const float*)d_in[0];
    const int*   EI      = (const int*)d_in[1];
    const float* EW      = (const float*)d_in[2];
    const float* W_gcn   = (const float*)d_in[4];
    const float* b_gcn   = (const float*)d_in[5];
    const float* W_gat1  = (const float*)d_in[6];
    const float* a_src1  = (const float*)d_in[7];
    const float* a_dst1  = (const float*)d_in[8];
    const float* b_gat1  = (const float*)d_in[9];
    const float* W_gat2  = (const float*)d_in[10];
    const float* a_src2  = (const float*)d_in[11];
    const float* a_dst2  = (const float*)d_in[12];
    const float* b_gat2  = (const float*)d_in[13];
    const float* W_fc1   = (const float*)d_in[14];
    const float* b_fc1   = (const float*)d_in[15];
    const float* W_fc2   = (const float*)d_in[16];
    const float* b_fc2   = (const float*)d_in[17];
    const float* pro_bias= (const float*)d_in[18];
    const float* W_g1    = (const float*)d_in[19];
    const float* b_g1    = (const float*)d_in[20];
    const float* W_g2    = (const float*)d_in[21];
    const float* b_g2    = (const float*)d_in[22];
    float* OUT = (float*)d_out;

    float* ws = (float*)d_ws;
    float*    dis     = ws + O_DIS;
    int*      counts  = (int*)(ws + O_CNT);
    float*    wdeg    = ws + O_WDEG;
    int*      indptr  = (int*)(ws + O_IDP);
    int*      bsum    = (int*)(ws + O_BSUM);
    int*      csr_src = (int*)(ws + O_CSR_S);
    float*    csr_w   = ws + O_CSR_W;
    float*    esd     = ws + O_ESD;
    u32*      genc    = (u32*)(ws + O_GE);
    float*    cmp1    = ws + O_CMP1;
    float*    cmp2    = ws + O_CMP2;
    u16*      U       = (u16*)(ws + O_U);
    u16*      ABX     = U + U_ABX;
    u16*      AGG     = U + U_AGG;
    u16*      y       = U + U_Y;
    u16*      ABF     = U + U_ABF;
    u16*      ABG     = U + U_ABG;
    u16*      BTG     = U + U_BTG;
    u16*      BTGCN   = U + U_BTGCN;
    u16*      BTY1    = U + U_BTY1;
    u16*      BTY2    = U + U_BTY2;
    u16*      BTS1    = U + U_BTS1;
    u16*      BTS2    = U + U_BTS2;

    const int EB = (N_EDGES + 255) / 256;
    const int NB4 = N_NODES / 4;   // 7500
    const int GB_ = MP / 64;       // 469

    // ---- weight/X conversions + zeroing ----
    k_cvtW<<<(SW_TOT + 255) / 256, 256, 0, stream>>>(
        W_fc1, W_fc2, W_gcn, W_gat1, W_gat2, W_g1, W_g2, X,
        a_src1, a_dst1, a_src2, a_dst2,
        BTG, BTGCN, BTY1, BTY2, BTS1, BTS2, cmp1, cmp2, ABX,
        (u32*)counts, (u32*)wdeg, genc);

    // ---- CSR build ----
    k_count<<<EB, 256, 0, stream>>>(EI, EW, counts, wdeg);
    k_bsum<<<NBLK, 256, 0, stream>>>(counts, wdeg, bsum, dis);
    k_apply<<<NBLK, 256, 0, stream>>>(counts, bsum, indptr);
    k_scatter<<<EB, 256, 0, stream>>>(EI, EW, indptr, counts, csr_src, csr_w);

    // ---- GCN: aggregate X-domain, then GEMM (emits x1 -> ABF/ABG + esd1) ----
    k_gcn_aggX<<<NB4, 256, 0, stream>>>(ABX, indptr, csr_src, csr_w, dis, AGG);
    k_gemm<3, true><<<GB_, 256, 0, stream>>>(AGG, BTGCN, N_NODES, HID, 64,
                                             nullptr, ABF, 160, 160, ABG, 288, 132,
                                             b_gcn, 1, 0, nullptr, nullptr, nullptr,
                                             cmp1, esd);

    // ---- GAT layer 1 ----
    k_gat_node<<<NB4, 256, 0, stream>>>(ABF, esd, indptr, csr_src, y);
    k_gemm<3, false><<<GB_, 256, 0, stream>>>(y, BTY1, N_NODES, HID, YW,
                                              nullptr, ABG, 288, 0, nullptr, 0, 0,
                                              b_gat1, 1, 0, nullptr, nullptr, nullptr,
                                              nullptr, nullptr);
    // gate 1: x2 -> ABF (x-table layer 2) + ABG cols 132.. + esd2
    k_gemm<3, true><<<GB_, 256, 0, stream>>>(ABG, BTG, N_NODES, HID, 288,
                                             nullptr, ABF, 160, 160, ABG, 288, 132,
                                             b_fc1, 0, 1, b_fc2, pro_bias, nullptr,
                                             cmp2, esd);

    // ---- GAT layer 2 ----
    k_gat_node<<<NB4, 256, 0, stream>>>(ABF, esd, indptr, csr_src, y);
    k_gemm<3, false><<<GB_, 256, 0, stream>>>(y, BTY2, N_NODES, HID, YW,
                                              nullptr, ABG, 288, 0, nullptr, 0, 0,
                                              b_gat2, 0, 0, nullptr, nullptr, nullptr,
                                              nullptr, nullptr);
    // gate 2: pool directly into genc
    k_gemm<3, false><<<GB_, 256, 0, stream>>>(ABG, BTG, N_NODES, HID, 288,
                                              nullptr, nullptr, 0, 0, nullptr, 0, 0,
                                              b_fc1, 0, 1, b_fc2, pro_bias, genc,
                                              nullptr, nullptr);

    // ---- MLP head ----
    k_head<<<GRAPHS, 256, 0, stream>>>(genc, BTS1, BTS2, b_g1, b_g2, OUT);
}

// Round 14
// 401.973 us; speedup vs baseline: 1.1991x; 1.1991x over previous
//
#include <hip/hip_runtime.h>

// ---------------- problem constants ----------------
constexpr int N_NODES = 30000;
constexpr int N_EDGES = 300000;
constexpr int GRAPHS  = 64;
constexpr int F_IN    = 33;
constexpr int HID     = 132;
constexpr int HID4    = 528;
constexpr int OUT_DIM = 128;
constexpr int GFC     = 1024;
constexpr int MP      = 30016;
constexpr int CAP     = 128;
constexpr int NBLK    = 118;           // ceil(N_NODES/256)
constexpr int YW      = 544;           // y row stride u16

typedef unsigned int u32;
typedef unsigned short u16;

// ---------------- workspace layout ----------------
constexpr size_t rnd64(size_t x) { return (x + 63) & ~(size_t)63; }
constexpr size_t O_DIS   = 0;
constexpr size_t O_CNT   = O_DIS   + rnd64(N_NODES);
constexpr size_t O_WDEG  = O_CNT   + rnd64(N_NODES);
constexpr size_t O_IDP   = O_WDEG  + rnd64(N_NODES);
constexpr size_t O_BSUM  = O_IDP   + rnd64(N_NODES + 1);
constexpr size_t O_CSR_S = O_BSUM  + rnd64(128);
constexpr size_t O_CSR_W = O_CSR_S + rnd64(N_EDGES);
constexpr size_t O_ESD   = O_CSR_W + rnd64(N_EDGES);                 // float, N*8
constexpr size_t O_GE    = O_ESD   + rnd64((size_t)N_NODES * 8);     // u32, G*HID
constexpr size_t O_CMP1  = O_GE    + rnd64(GRAPHS * HID);            // float, 8*132
constexpr size_t O_CMP2  = O_CMP1  + rnd64(8 * HID);
constexpr size_t O_TMP   = O_CMP2  + rnd64(8 * HID);                 // float, E*4
// u16 region
constexpr size_t O_U     = O_TMP   + rnd64((size_t)N_EDGES * 4);
constexpr size_t U_ABX   = 0;                                        // [MP,64] X bf16
constexpr size_t U_AGG   = U_ABX  + rnd64((size_t)MP * 64);          // [MP,64] aggX
constexpr size_t U_Y     = U_AGG  + rnd64((size_t)MP * 64);          // [MP,YW]
constexpr size_t U_ABF   = U_Y    + rnd64((size_t)MP * YW);          // [MP,160] x table
constexpr size_t U_ABG   = U_ABF  + rnd64((size_t)MP * 160);         // [MP,288]
constexpr size_t U_BTG   = U_ABG  + rnd64((size_t)MP * 288);         // [192,288]
constexpr size_t U_BTGCN = U_BTG  + rnd64(192 * 288);                // [192,64]
constexpr size_t U_BTY1  = U_BTGCN+ rnd64(192 * 64);                 // [192,544]
constexpr size_t U_BTY2  = U_BTY1 + rnd64(192 * 544);                // [192,544]
constexpr size_t U_BTS1  = U_BTY2 + rnd64(192 * 544);                // [1024,160]
constexpr size_t U_BTS2  = U_BTS1 + rnd64(1024 * 160);               // [128,1024]

// ---------------- bf16 helpers ----------------
__device__ inline u16 f2bf(float f) {
    u32 u = __float_as_uint(f);
    return (u16)((u + 0x7fffu + ((u >> 16) & 1u)) >> 16);
}
__device__ inline u32 pk2(float a, float b) { return (u32)f2bf(a) | ((u32)f2bf(b) << 16); }
__device__ inline float bflo(u32 w) { return __uint_as_float(w << 16); }
__device__ inline float bfhi(u32 w) { return __uint_as_float(w & 0xffff0000u); }
__device__ inline float bf1(u16 x) { return __uint_as_float((u32)x << 16); }
__device__ inline u32 encf(float x) {
    u32 u = __float_as_uint(x);
    return (u & 0x80000000u) ? ~u : (u | 0x80000000u);
}
__device__ inline float decf(u32 e) {
    u32 u = (e & 0x80000000u) ? (e & 0x7fffffffu) : ~e;
    return __uint_as_float(u);
}
__device__ inline float fexp(float x) { return __expf(x); }   // native v_exp_f32

typedef __attribute__((ext_vector_type(8))) short s8b;
typedef __attribute__((ext_vector_type(4))) float f32x4;

// ---------------- CSR build ----------------
__global__ void k_count(const int* __restrict__ ei, const float* __restrict__ ew,
                        int* __restrict__ counts, float* __restrict__ wdeg) {
    int e = blockIdx.x * 256 + threadIdx.x;
    if (e < N_EDGES) {
        int dst = ei[N_EDGES + e];
        atomicAdd(&counts[dst], 1);
        atomicAdd(&wdeg[dst], ew[e]);
    }
}

__global__ __launch_bounds__(256) void k_bsum(const int* __restrict__ counts,
                                              const float* __restrict__ wdeg,
                                              int* __restrict__ bsum,
                                              float* __restrict__ dis) {
    int i = blockIdx.x * 256 + threadIdx.x;
    int v = (i < N_NODES) ? counts[i] : 0;
    if (i < N_NODES) {
        float d = 1.f + wdeg[i];
        dis[i] = (d > 0.f) ? rsqrtf(fmaxf(d, 1e-12f)) : 0.f;
    }
    int x = v;
    #pragma unroll
    for (int off = 1; off < 64; off <<= 1) x += __shfl_xor(x, off);
    __shared__ int ws4[4];
    if ((threadIdx.x & 63) == 0) ws4[threadIdx.x >> 6] = x;
    __syncthreads();
    if (threadIdx.x == 0) bsum[blockIdx.x] = ws4[0] + ws4[1] + ws4[2] + ws4[3];
}

__global__ __launch_bounds__(256) void k_apply(int* __restrict__ counts,
                                               const int* __restrict__ bsum,
                                               int* __restrict__ indptr) {
    __shared__ int s1[4], s2[4];
    const int b = blockIdx.x;
    const int tid = threadIdx.x, lane = tid & 63, w = tid >> 6;
    int part = (tid < b) ? bsum[tid] : 0;
    #pragma unroll
    for (int off = 1; off < 64; off <<= 1) part += __shfl_xor(part, off);
    if (lane == 0) s1[w] = part;
    int i = b * 256 + tid;
    int v = (i < N_NODES) ? counts[i] : 0;
    int x = v;
    #pragma unroll
    for (int off = 1; off < 64; off <<= 1) {
        int y = __shfl_up(x, off);
        if (lane >= off) x += y;
    }
    if (lane == 63) s2[w] = x;
    __syncthreads();
    int add = s1[0] + s1[1] + s1[2] + s1[3];
    for (int k2 = 0; k2 < w; ++k2) add += s2[k2];
    if (i < N_NODES) {
        indptr[i] = add + x - v;
        counts[i] = 0;
    }
    if (i == N_NODES) indptr[N_NODES] = N_EDGES;
}

__global__ void k_scatter(const int* __restrict__ ei, const float* __restrict__ ew,
                          const int* __restrict__ indptr, int* __restrict__ cursor,
                          int* __restrict__ csr_src, float* __restrict__ csr_w) {
    int e = blockIdx.x * 256 + threadIdx.x;
    if (e >= N_EDGES) return;
    int src = ei[e];
    int dst = ei[N_EDGES + e];
    int pos = indptr[dst] + atomicAdd(&cursor[dst], 1);
    csr_src[pos] = src;
    csr_w[pos] = ew[e];
}

// ---------------- merged weight + X conversion + zeroing ----------------
constexpr int S0 = 192 * 288;
constexpr int S1 = 192 * 64;
constexpr int S2 = 192 * 544;
constexpr int S3 = 192 * 544;
constexpr int S4 = 1024 * 160;
constexpr int S5 = 128 * 1024;
constexpr int S6 = N_NODES * 64;
constexpr int S7 = 2 * 8 * HID;
constexpr int S8 = N_NODES + N_NODES + GRAPHS * HID;
constexpr int SW_TOT = S0 + S1 + S2 + S3 + S4 + S5 + S6 + S7 + S8;

__global__ void k_cvtW(const float* __restrict__ Wfc1, const float* __restrict__ Wfc2,
                       const float* __restrict__ Wgcn, const float* __restrict__ Wgat1,
                       const float* __restrict__ Wgat2, const float* __restrict__ Wg1,
                       const float* __restrict__ Wg2, const float* __restrict__ X,
                       const float* __restrict__ as1, const float* __restrict__ ad1,
                       const float* __restrict__ as2, const float* __restrict__ ad2,
                       u16* __restrict__ BTG, u16* __restrict__ BTGCN,
                       u16* __restrict__ BTY1, u16* __restrict__ BTY2,
                       u16* __restrict__ BTS1, u16* __restrict__ BTS2,
                       float* __restrict__ cmp1, float* __restrict__ cmp2,
                       u16* __restrict__ ABX,
                       u32* __restrict__ zc, u32* __restrict__ zw, u32* __restrict__ zg) {
    int idx = blockIdx.x * 256 + threadIdx.x;
    if (idx < S0) {
        int n = idx / 288, k = idx - n * 288;
        u16 v = 0;
        if (n < HID) {
            if (k < HID) v = f2bf(Wfc1[(size_t)k * HID + n]);
            else if (k < 2 * HID) v = f2bf(Wfc2[(size_t)(k - HID) * HID + n]);
        }
        BTG[idx] = v;
        return;
    }
    idx -= S0;
    if (idx < S1) {
        int n = idx / 64, k = idx - n * 64;
        BTGCN[idx] = (k < F_IN && n < HID) ? f2bf(Wgcn[(size_t)k * HID + n]) : (u16)0;
        return;
    }
    idx -= S1;
    if (idx < S2 + S3) {
        int l = (idx >= S2);
        int li = l ? (idx - S2) : idx;
        int n = li / 544, c = li - n * 544;
        int k = c / 136, j = c - k * 136;
        const float* W = l ? Wgat2 : Wgat1;
        u16 v = 0;
        if (n < HID && j < HID) v = f2bf(0.25f * W[(size_t)j * HID4 + k * HID + n]);
        (l ? BTY2 : BTY1)[li] = v;
        return;
    }
    idx -= S2 + S3;
    if (idx < S4) {
        int n = idx / 160, k = idx - n * 160;
        BTS1[idx] = (k < HID) ? f2bf(Wg1[(size_t)k * GFC + n]) : (u16)0;
        return;
    }
    idx -= S4;
    if (idx < S5) {
        int n = idx / 1024, k = idx - n * 1024;
        BTS2[idx] = f2bf(Wg2[(size_t)k * OUT_DIM + n]);
        return;
    }
    idx -= S5;
    if (idx < S6) {
        int r = idx / 64, k = idx - r * 64;
        ABX[idx] = (k < F_IN) ? f2bf(X[(size_t)r * F_IN + k]) : (u16)0;
        return;
    }
    idx -= S6;
    if (idx < S7) {
        int l = idx / (8 * HID); idx -= l * (8 * HID);
        int q = idx / HID;  int c = idx - q * HID;
        int k = q & 3;
        const float* W = l ? Wgat2 : Wgat1;
        const float* a = (q < 4) ? (l ? as2 : as1) : (l ? ad2 : ad1);
        const float* wr = W + (size_t)c * HID4 + k * HID;
        const float* ar = a + k * HID;
        float sum = 0.f;
        for (int cc = 0; cc < HID; ++cc) sum += wr[cc] * ar[cc];
        (l ? cmp2 : cmp1)[q * HID + c] = sum;
        return;
    }
    idx -= S7;
    if (idx < S8) {
        if (idx < N_NODES) zc[idx] = 0;
        else if (idx < 2 * N_NODES) zw[idx - N_NODES] = 0;
        else zg[idx - 2 * N_NODES] = 0;
    }
}

// ---------------- MFMA bf16 GEMM, NT column-tiles, optional fused esd --------
template <int NT, bool ESD>
__global__ __launch_bounds__(256) void k_gemm(
    const u16* __restrict__ A, const u16* __restrict__ Bt,
    int M, int N, int Kp,
    float* __restrict__ Cf,
    u16* __restrict__ Cb, int ldcb, int padN,
    u16* __restrict__ Cb2, int ldcb2, int coff2,
    const float* __restrict__ bias, int relu, int gate,
    const float* __restrict__ b2, const float* __restrict__ pb,
    u32* __restrict__ genc,
    const float* __restrict__ compG, float* __restrict__ esdOut) {
    __shared__ float xs[ESD ? 64 : 1][134];
    __shared__ float cmp[ESD ? 8 : 1][132];
    const int bm = blockIdx.x * 64;
    const int w = threadIdx.x >> 6;
    const int lane = threadIdx.x & 63;
    const int m16 = lane & 15;
    const int quad = lane >> 4;
    const u16* Ab = A + (size_t)(bm + m16) * Kp + quad * 8;
    const u16* Bb[NT];
    #pragma unroll
    for (int j = 0; j < NT; ++j)
        Bb[j] = Bt + (size_t)(j * 64 + w * 16 + m16) * Kp + quad * 8;
    f32x4 acc[NT][4];
    #pragma unroll
    for (int j = 0; j < NT; ++j)
        #pragma unroll
        for (int r = 0; r < 4; ++r) acc[j][r] = (f32x4){0.f, 0.f, 0.f, 0.f};
    for (int k0 = 0; k0 < Kp; k0 += 32) {
        s8b a0 = *(const s8b*)(Ab + k0);
        s8b a1 = *(const s8b*)(Ab + (size_t)16 * Kp + k0);
        s8b a2 = *(const s8b*)(Ab + (size_t)32 * Kp + k0);
        s8b a3 = *(const s8b*)(Ab + (size_t)48 * Kp + k0);
        #pragma unroll
        for (int j = 0; j < NT; ++j) {
            s8b b = *(const s8b*)(Bb[j] + k0);
            acc[j][0] = __builtin_amdgcn_mfma_f32_16x16x32_bf16(a0, b, acc[j][0], 0, 0, 0);
            acc[j][1] = __builtin_amdgcn_mfma_f32_16x16x32_bf16(a1, b, acc[j][1], 0, 0, 0);
            acc[j][2] = __builtin_amdgcn_mfma_f32_16x16x32_bf16(a2, b, acc[j][2], 0, 0, 0);
            acc[j][3] = __builtin_amdgcn_mfma_f32_16x16x32_bf16(a3, b, acc[j][3], 0, 0, 0);
        }
    }
    const int g0 = (bm * GRAPHS) / N_NODES;
    int gend = bm + 63; if (gend >= M) gend = M - 1;
    const int g1 = (gend * GRAPHS) / N_NODES;
    #pragma unroll
    for (int j = 0; j < NT; ++j) {
        const int col = j * 64 + w * 16 + m16;
        const bool colok = col < N;
        float bsum = 0.f;
        if (colok) {
            if (gate) bsum = bias[col] + b2[col] + pb[col];
            else if (bias) bsum = bias[col];
        }
        float mx0 = -3.4e38f, mx1 = -3.4e38f;
        #pragma unroll
        for (int r = 0; r < 4; ++r) {
            #pragma unroll
            for (int jj = 0; jj < 4; ++jj) {
                int row = bm + r * 16 + quad * 4 + jj;
                if (row >= M || !colok) continue;
                float v = acc[j][r][jj] + bsum;
                float res;
                if (gate) {
                    float z = 1.f / (1.f + fexp(-v));
                    float xcv = bf1(A[(size_t)row * Kp + col]);
                    float xpv = bf1(A[(size_t)row * Kp + 132 + col]);
                    res = z * xcv + (1.f - z) * xpv;
                } else {
                    if (relu) v = fmaxf(v, 0.f);
                    res = v;
                }
                if constexpr (ESD) {
                    if (col < 132) xs[row - bm][col] = res;
                }
                if (genc) {
                    int gid = (row * GRAPHS) / N_NODES;
                    if (gid == g0) mx0 = fmaxf(mx0, res);
                    else           mx1 = fmaxf(mx1, res);
                }
                if (Cf) Cf[(size_t)row * N + col] = res;
                if (Cb) Cb[(size_t)row * ldcb + col] = f2bf(res);
                if (Cb2) Cb2[(size_t)row * ldcb2 + coff2 + col] = f2bf(res);
            }
        }
        if (genc && colok) {
            mx0 = fmaxf(mx0, __shfl_xor(mx0, 16));
            mx0 = fmaxf(mx0, __shfl_xor(mx0, 32));
            if (g1 != g0) {
                mx1 = fmaxf(mx1, __shfl_xor(mx1, 16));
                mx1 = fmaxf(mx1, __shfl_xor(mx1, 32));
            }
            if (quad == 0) {
                atomicMax(&genc[g0 * HID + col], encf(mx0));
                if (g1 != g0) atomicMax(&genc[g1 * HID + col], encf(mx1));
            }
        }
    }
    if constexpr (ESD) {
        for (int i2 = threadIdx.x; i2 < 8 * HID; i2 += 256)
            cmp[i2 / HID][i2 % HID] = compG[i2];
        __syncthreads();
        int row = threadIdx.x >> 2, q = threadIdx.x & 3;
        if (bm + row < M) {
            float s0 = 0.f, s1 = 0.f;
            for (int c = 0; c < HID; ++c) {
                float xv = xs[row][c];
                s0 += xv * cmp[q][c];
                s1 += xv * cmp[q + 4][c];
            }
            esdOut[(size_t)(bm + row) * 8 + q] = s0;
            esdOut[(size_t)(bm + row) * 8 + 4 + q] = s1;
        }
    }
}

// ---------------- GCN aggregate in X-domain (33 ch, 2 edges/wave-iter) -------
__global__ __launch_bounds__(256) void k_gcn_aggX(
    const u16* __restrict__ xb, const int* __restrict__ indptr,
    const int* __restrict__ csr_src, const float* __restrict__ csr_w,
    const float* __restrict__ dis, u16* __restrict__ aggx) {
    const int w = threadIdx.x >> 6, t = threadIdx.x & 63;
    const int i = blockIdx.x * 4 + w;
    const int g = t >> 5;
    const int c = t & 31;
    const float di = dis[i];
    const int s = indptr[i], e = indptr[i + 1];
    const u32* X32 = (const u32*)xb;
    float aLo = 0.f, aHi = 0.f;
    int j = s;
    for (; j + 3 < e; j += 4) {
        int j0 = j + g, j1 = j + 2 + g;
        int s0 = csr_src[j0], s1 = csr_src[j1];
        float n0 = dis[s0] * csr_w[j0] * di;
        float n1 = dis[s1] * csr_w[j1] * di;
        u32 v0 = X32[(size_t)s0 * 32 + c];
        u32 v1 = X32[(size_t)s1 * 32 + c];
        aLo += n0 * bflo(v0) + n1 * bflo(v1);
        aHi += n0 * bfhi(v0) + n1 * bfhi(v1);
    }
    for (; j < e; j += 2) {
        int jj = j + g;
        if (jj < e) {
            int s0 = csr_src[jj];
            float n0 = dis[s0] * csr_w[jj] * di;
            u32 v0 = X32[(size_t)s0 * 32 + c];
            aLo += n0 * bflo(v0);
            aHi += n0 * bfhi(v0);
        }
    }
    aLo += __shfl_xor(aLo, 32);
    aHi += __shfl_xor(aHi, 32);
    if (t < 32) {
        float nself = di * di;
        u32 v = X32[(size_t)i * 32 + t];
        aLo += nself * bflo(v);
        aHi += nself * bfhi(v);
        ((u32*)aggx)[(size_t)i * 32 + t] = pk2(aLo, aHi);
    }
}

// ---------------- GAT softmax (no-max, distributed exp) + x-domain aggregate -
__global__ __launch_bounds__(256) void k_gat_node(
    const u16* __restrict__ xt, const float* __restrict__ esd,
    const int* __restrict__ indptr, const int* __restrict__ csr_src,
    float* __restrict__ tmp, u16* __restrict__ y) {
    __shared__ __align__(16) float al[4][CAP * 4];
    __shared__ int srcl[4][CAP];
    const int w = threadIdx.x >> 6, t = threadIdx.x & 63;
    const int i = blockIdx.x * 4 + w;
    const int k = t & 3;
    const int s = indptr[i];
    const int deg = indptr[i + 1] - s;
    const bool fast = (deg <= CAP);
    const float edk = esd[i * 8 + 4 + k];
    float eself = esd[i * 8 + k] + edk;
    eself = (eself >= 0.f) ? eself : 0.2f * eself;
    // distributed exp pass: 16 edges x 4 heads per wave-iter
    float dsum = 0.f;
    for (int j0 = 0; j0 < deg; j0 += 16) {
        int j = j0 + (t >> 2);
        if (j < deg) {
            int src = csr_src[s + j];
            float e = esd[src * 8 + k] + edk;
            e = (e >= 0.f) ? e : 0.2f * e;
            float ex = fexp(e);
            if (fast) { al[w][j * 4 + k] = ex; if (k == 0) srcl[w][j] = src; }
            else tmp[(size_t)(s + j) * 4 + k] = ex;
            dsum += ex;
        }
    }
    dsum += __shfl_xor(dsum, 4);
    dsum += __shfl_xor(dsum, 8);
    dsum += __shfl_xor(dsum, 16);
    dsum += __shfl_xor(dsum, 32);
    float exs = fexp(eself);
    dsum += exs;
    float inv = 1.f / dsum;
    float aself = exs * inv;
    float a0 = __shfl(aself, 0), a1 = __shfl(aself, 1);
    float a2 = __shfl(aself, 2), a3 = __shfl(aself, 3);
    if (fast) {
        for (int idx = t; idx < deg * 4; idx += 64) al[w][idx] *= inv;
    }
    const u32* X = (const u32*)xt;   // row stride 80 u32
    float yL0, yH0, yL1, yH1, yL2, yH2, yL3, yH3;
    float zL0 = 0, zH0 = 0, zL1 = 0, zH1 = 0, zL2 = 0, zH2 = 0, zL3 = 0, zH3 = 0;
    {
        u32 v = X[(size_t)i * 80 + t];
        float lo = bflo(v), hi = bfhi(v);
        yL0 = a0 * lo; yH0 = a0 * hi;
        yL1 = a1 * lo; yH1 = a1 * hi;
        yL2 = a2 * lo; yH2 = a2 * hi;
        yL3 = a3 * lo; yH3 = a3 * hi;
        if (t < 2) {
            u32 v2 = X[(size_t)i * 80 + 64 + t];
            float l2 = bflo(v2), h2 = bfhi(v2);
            zL0 = a0 * l2; zH0 = a0 * h2;
            zL1 = a1 * l2; zH1 = a1 * h2;
            zL2 = a2 * l2; zH2 = a2 * h2;
            zL3 = a3 * l2; zH3 = a3 * h2;
        }
    }
    if (fast) {
        int j = 0;
        for (; j + 3 < deg; j += 4) {
            int s0 = srcl[w][j], s1 = srcl[w][j + 1], s2 = srcl[w][j + 2], s3 = srcl[w][j + 3];
            u32 v0 = X[(size_t)s0 * 80 + t];
            u32 v1 = X[(size_t)s1 * 80 + t];
            u32 v2 = X[(size_t)s2 * 80 + t];
            u32 v3 = X[(size_t)s3 * 80 + t];
            float4 x0 = *(const float4*)&al[w][j * 4];
            float4 x1 = *(const float4*)&al[w][j * 4 + 4];
            float4 x2 = *(const float4*)&al[w][j * 4 + 8];
            float4 x3 = *(const float4*)&al[w][j * 4 + 12];
            float l0 = bflo(v0), h0 = bfhi(v0), l1 = bflo(v1), h1 = bfhi(v1);
            float l2 = bflo(v2), h2 = bfhi(v2), l3 = bflo(v3), h3 = bfhi(v3);
            yL0 += x0.x * l0 + x1.x * l1 + x2.x * l2 + x3.x * l3;
            yH0 += x0.x * h0 + x1.x * h1 + x2.x * h2 + x3.x * h3;
            yL1 += x0.y * l0 + x1.y * l1 + x2.y * l2 + x3.y * l3;
            yH1 += x0.y * h0 + x1.y * h1 + x2.y * h2 + x3.y * h3;
            yL2 += x0.z * l0 + x1.z * l1 + x2.z * l2 + x3.z * l3;
            yH2 += x0.z * h0 + x1.z * h1 + x2.z * h2 + x3.z * h3;
            yL3 += x0.w * l0 + x1.w * l1 + x2.w * l2 + x3.w * l3;
            yH3 += x0.w * h0 + x1.w * h1 + x2.w * h2 + x3.w * h3;
            if (t < 2) {
                u32 e0 = X[(size_t)s0 * 80 + 64 + t];
                u32 e1 = X[(size_t)s1 * 80 + 64 + t];
                u32 e2 = X[(size_t)s2 * 80 + 64 + t];
                u32 e3 = X[(size_t)s3 * 80 + 64 + t];
                float el0 = bflo(e0), eh0 = bfhi(e0), el1 = bflo(e1), eh1 = bfhi(e1);
                float el2 = bflo(e2), eh2 = bfhi(e2), el3 = bflo(e3), eh3 = bfhi(e3);
                zL0 += x0.x * el0 + x1.x * el1 + x2.x * el2 + x3.x * el3;
                zH0 += x0.x * eh0 + x1.x * eh1 + x2.x * eh2 + x3.x * eh3;
                zL1 += x0.y * el0 + x1.y * el1 + x2.y * el2 + x3.y * el3;
                zH1 += x0.y * eh0 + x1.y * eh1 + x2.y * eh2 + x3.y * eh3;
                zL2 += x0.z * el0 + x1.z * el1 + x2.z * el2 + x3.z * el3;
                zH2 += x0.z * eh0 + x1.z * eh1 + x2.z * eh2 + x3.z * eh3;
                zL3 += x0.w * el0 + x1.w * el1 + x2.w * el2 + x3.w * el3;
                zH3 += x0.w * eh0 + x1.w * eh1 + x2.w * eh2 + x3.w * eh3;
            }
        }
        for (; j < deg; ++j) {
            int s0 = srcl[w][j];
            u32 v0 = X[(size_t)s0 * 80 + t];
            float4 x0 = *(const float4*)&al[w][j * 4];
            float l0 = bflo(v0), h0 = bfhi(v0);
            yL0 += x0.x * l0; yH0 += x0.x * h0;
            yL1 += x0.y * l0; yH1 += x0.y * h0;
            yL2 += x0.z * l0; yH2 += x0.z * h0;
            yL3 += x0.w * l0; yH3 += x0.w * h0;
            if (t < 2) {
                u32 e0 = X[(size_t)s0 * 80 + 64 + t];
                float el0 = bflo(e0), eh0 = bfhi(e0);
                zL0 += x0.x * el0; zH0 += x0.x * eh0;
                zL1 += x0.y * el0; zH1 += x0.y * eh0;
                zL2 += x0.z * el0; zH2 += x0.z * eh0;
                zL3 += x0.w * el0; zH3 += x0.w * eh0;
            }
        }
    } else {
        float inv0 = __shfl(inv, 0), inv1 = __shfl(inv, 1);
        float inv2 = __shfl(inv, 2), inv3 = __shfl(inv, 3);
        const float4* tmp4 = (const float4*)tmp;
        for (int j = 0; j < deg; ++j) {
            int src = csr_src[s + j];
            float4 ax = tmp4[s + j];
            float b0 = ax.x * inv0, b1 = ax.y * inv1, b2 = ax.z * inv2, b3 = ax.w * inv3;
            u32 v0 = X[(size_t)src * 80 + t];
            float l0 = bflo(v0), h0 = bfhi(v0);
            yL0 += b0 * l0; yH0 += b0 * h0;
            yL1 += b1 * l0; yH1 += b1 * h0;
            yL2 += b2 * l0; yH2 += b2 * h0;
            yL3 += b3 * l0; yH3 += b3 * h0;
            if (t < 2) {
                u32 e0 = X[(size_t)src * 80 + 64 + t];
                float el0 = bflo(e0), eh0 = bfhi(e0);
                zL0 += b0 * el0; zH0 += b0 * eh0;
                zL1 += b1 * el0; zH1 += b1 * eh0;
                zL2 += b2 * el0; zH2 += b2 * eh0;
                zL3 += b3 * el0; zH3 += b3 * eh0;
            }
        }
    }
    u32* yr = (u32*)(y + (size_t)i * YW);
    yr[t]       = pk2(yL0, yH0);
    yr[68 + t]  = pk2(yL1, yH1);
    yr[136 + t] = pk2(yL2, yH2);
    yr[204 + t] = pk2(yL3, yH3);
    if (t < 2) {
        yr[64 + t]  = pk2(zL0, zH0);
        yr[132 + t] = pk2(zL1, zH1);
        yr[200 + t] = pk2(zL2, zH2);
        yr[268 + t] = pk2(zL3, zH3);
    } else if (t < 4) {
        yr[64 + t] = 0; yr[132 + t] = 0; yr[200 + t] = 0; yr[268 + t] = 0;
    }
}

// ---------------- MLP head ----------------
__global__ __launch_bounds__(256) void k_head(
    const u32* __restrict__ genc, const u16* __restrict__ BTS1,
    const u16* __restrict__ BTS2, const float* __restrict__ b_g1,
    const float* __restrict__ b_g2, float* __restrict__ out) {
    __shared__ u32 g_sm[66];
    __shared__ float h_sm[GFC];
    __shared__ float part[OUT_DIM];
    const int g = blockIdx.x;
    const int tid = threadIdx.x;
    if (tid < 66) {
        float a0 = decf(genc[g * HID + 2 * tid]);
        float a1 = decf(genc[g * HID + 2 * tid + 1]);
        g_sm[tid] = pk2(a0, a1);
    }
    __syncthreads();
    #pragma unroll
    for (int r = 0; r < 4; ++r) {
        int o = tid + 256 * r;
        const u32* wr = (const u32*)(BTS1 + (size_t)o * 160);
        float acc = 0.f;
        for (int c = 0; c < 66; ++c) {
            u32 wv = wr[c], gv = g_sm[c];
            acc += bflo(wv) * bflo(gv) + bfhi(wv) * bfhi(gv);
        }
        acc = fmaxf(acc + b_g1[o], 0.f);
        h_sm[o] = __uint_as_float((u32)f2bf(acc) << 16);
    }
    __syncthreads();
    const int o = tid & 127, half = tid >> 7;
    const u32* wr2 = (const u32*)(BTS2 + (size_t)o * 1024 + half * 512);
    const float* hh = h_sm + half * 512;
    float acc = 0.f;
    for (int c = 0; c < 256; ++c) {
        u32 wv = wr2[c];
        acc += bflo(wv) * hh[2 * c] + bfhi(wv) * hh[2 * c + 1];
    }
    if (half == 1) part[o] = acc;
    __syncthreads();
    if (half == 0) out[(size_t)g * OUT_DIM + o] = acc + part[o] + b_g2[o];
}

// ---------------- launch ----------------
extern "C" void kernel_launch(void* const* d_in, const int* in_sizes, int n_in,
                              void* d_out, int out_size, void* d_ws, size_t ws_size,
                              hipStream_t stream) {
    const float* X       = (const float*)d_in[0];
    const int*   EI      = (const int*)d_in[1];
    const float* EW      = (const float*)d_in[2];
    const float* W_gcn   = (const float*)d_in[4];
    const float* b_gcn   = (const float*)d_in[5];
    const float* W_gat1  = (const float*)d_in[6];
    const float* a_src1  = (const float*)d_in[7];
    const float* a_dst1  = (const float*)d_in[8];
    const float* b_gat1  = (const float*)d_in[9];
    const float* W_gat2  = (const float*)d_in[10];
    const float* a_src2  = (const float*)d_in[11];
    const float* a_dst2  = (const float*)d_in[12];
    const float* b_gat2  = (const float*)d_in[13];
    const float* W_fc1   = (const float*)d_in[14];
    const float* b_fc1   = (const float*)d_in[15];
    const float* W_fc2   = (const float*)d_in[16];
    const float* b_fc2   = (const float*)d_in[17];
    const float* pro_bias= (const float*)d_in[18];
    const float* W_g1    = (const float*)d_in[19];
    const float* b_g1    = (const float*)d_in[20];
    const float* W_g2    = (const float*)d_in[21];
    const float* b_g2    = (const float*)d_in[22];
    float* OUT = (float*)d_out;

    float* ws = (float*)d_ws;
    float*    dis     = ws + O_DIS;
    int*      counts  = (int*)(ws + O_CNT);
    float*    wdeg    = ws + O_WDEG;
    int*      indptr  = (int*)(ws + O_IDP);
    int*      bsum    = (int*)(ws + O_BSUM);
    int*      csr_src = (int*)(ws + O_CSR_S);
    float*    csr_w   = ws + O_CSR_W;
    float*    esd     = ws + O_ESD;
    u32*      genc    = (u32*)(ws + O_GE);
    float*    cmp1    = ws + O_CMP1;
    float*    cmp2    = ws + O_CMP2;
    float*    tmp     = ws + O_TMP;
    u16*      U       = (u16*)(ws + O_U);
    u16*      ABX     = U + U_ABX;
    u16*      AGG     = U + U_AGG;
    u16*      y       = U + U_Y;
    u16*      ABF     = U + U_ABF;
    u16*      ABG     = U + U_ABG;
    u16*      BTG     = U + U_BTG;
    u16*      BTGCN   = U + U_BTGCN;
    u16*      BTY1    = U + U_BTY1;
    u16*      BTY2    = U + U_BTY2;
    u16*      BTS1    = U + U_BTS1;
    u16*      BTS2    = U + U_BTS2;

    const int EB = (N_EDGES + 255) / 256;
    const int NB4 = N_NODES / 4;   // 7500
    const int GB_ = MP / 64;       // 469

    // ---- weight/X conversions + zeroing ----
    k_cvtW<<<(SW_TOT + 255) / 256, 256, 0, stream>>>(
        W_fc1, W_fc2, W_gcn, W_gat1, W_gat2, W_g1, W_g2, X,
        a_src1, a_dst1, a_src2, a_dst2,
        BTG, BTGCN, BTY1, BTY2, BTS1, BTS2, cmp1, cmp2, ABX,
        (u32*)counts, (u32*)wdeg, genc);

    // ---- CSR build ----
    k_count<<<EB, 256, 0, stream>>>(EI, EW, counts, wdeg);
    k_bsum<<<NBLK, 256, 0, stream>>>(counts, wdeg, bsum, dis);
    k_apply<<<NBLK, 256, 0, stream>>>(counts, bsum, indptr);
    k_scatter<<<EB, 256, 0, stream>>>(EI, EW, indptr, counts, csr_src, csr_w);

    // ---- GCN: aggregate X-domain, then GEMM (emits x1 -> ABF/ABG + esd1) ----
    k_gcn_aggX<<<NB4, 256, 0, stream>>>(ABX, indptr, csr_src, csr_w, dis, AGG);
    k_gemm<3, true><<<GB_, 256, 0, stream>>>(AGG, BTGCN, N_NODES, HID, 64,
                                             nullptr, ABF, 160, 160, ABG, 288, 132,
                                             b_gcn, 1, 0, nullptr, nullptr, nullptr,
                                             cmp1, esd);

    // ---- GAT layer 1 ----
    k_gat_node<<<NB4, 256, 0, stream>>>(ABF, esd, indptr, csr_src, tmp, y);
    k_gemm<3, false><<<GB_, 256, 0, stream>>>(y, BTY1, N_NODES, HID, YW,
                                              nullptr, ABG, 288, 0, nullptr, 0, 0,
                                              b_gat1, 1, 0, nullptr, nullptr, nullptr,
                                              nullptr, nullptr);
    // gate 1: x2 -> ABF (x-table layer 2) + ABG cols 132.. + esd2
    k_gemm<3, true><<<GB_, 256, 0, stream>>>(ABG, BTG, N_NODES, HID, 288,
                                             nullptr, ABF, 160, 160, ABG, 288, 132,
                                             b_fc1, 0, 1, b_fc2, pro_bias, nullptr,
                                             cmp2, esd);

    // ---- GAT layer 2 ----
    k_gat_node<<<NB4, 256, 0, stream>>>(ABF, esd, indptr, csr_src, tmp, y);
    k_gemm<3, false><<<GB_, 256, 0, stream>>>(y, BTY2, N_NODES, HID, YW,
                                              nullptr, ABG, 288, 0, nullptr, 0, 0,
                                              b_gat2, 0, 0, nullptr, nullptr, nullptr,
                                              nullptr, nullptr);
    // gate 2: pool directly into genc
    k_gemm<3, false><<<GB_, 256, 0, stream>>>(ABG, BTG, N_NODES, HID, 288,
                                              nullptr, nullptr, 0, 0, nullptr, 0, 0,
                                              b_fc1, 0, 1, b_fc2, pro_bias, genc,
                                              nullptr, nullptr);

    // ---- MLP head ----
    k_head<<<GRAPHS, 256, 0, stream>>>(genc, BTS1, BTS2, b_g1, b_g2, OUT);
}

// Round 15
// 390.772 us; speedup vs baseline: 1.2335x; 1.0287x over previous
//
#include <hip/hip_runtime.h>

// ---------------- problem constants ----------------
constexpr int N_NODES = 30000;
constexpr int N_EDGES = 300000;
constexpr int GRAPHS  = 64;
constexpr int F_IN    = 33;
constexpr int HID     = 132;
constexpr int HID4    = 528;
constexpr int OUT_DIM = 128;
constexpr int GFC     = 1024;
constexpr int MP      = 30016;
constexpr int CAP     = 128;
constexpr int NBLK    = 118;           // ceil(N_NODES/256)
constexpr int YW      = 544;           // y row stride u16

typedef unsigned int u32;
typedef unsigned short u16;

// ---------------- workspace layout ----------------
constexpr size_t rnd64(size_t x) { return (x + 63) & ~(size_t)63; }
constexpr size_t O_DIS   = 0;
constexpr size_t O_CNT   = O_DIS   + rnd64(N_NODES);
constexpr size_t O_WDEG  = O_CNT   + rnd64(N_NODES);
constexpr size_t O_IDP   = O_WDEG  + rnd64(N_NODES);
constexpr size_t O_BSUM  = O_IDP   + rnd64(N_NODES + 1);
constexpr size_t O_CSR_S = O_BSUM  + rnd64(128);
constexpr size_t O_CSR_W = O_CSR_S + rnd64(N_EDGES);
constexpr size_t O_ESD   = O_CSR_W + rnd64(N_EDGES);                 // float, N*8
constexpr size_t O_GE    = O_ESD   + rnd64((size_t)N_NODES * 8);     // u32, G*HID
constexpr size_t O_CMP1  = O_GE    + rnd64(GRAPHS * HID);            // float, 8*132
constexpr size_t O_CMP2  = O_CMP1  + rnd64(8 * HID);
constexpr size_t O_TMP   = O_CMP2  + rnd64(8 * HID);                 // float, E*4
// u16 region
constexpr size_t O_U     = O_TMP   + rnd64((size_t)N_EDGES * 4);
constexpr size_t U_ABX   = 0;                                        // [MP,64] X bf16
constexpr size_t U_AGG   = U_ABX  + rnd64((size_t)MP * 64);          // [MP,64] aggX
constexpr size_t U_Y     = U_AGG  + rnd64((size_t)MP * 64);          // [MP,YW]
constexpr size_t U_ABF   = U_Y    + rnd64((size_t)MP * YW);          // [MP,160] x table
constexpr size_t U_ABG   = U_ABF  + rnd64((size_t)MP * 160);         // [MP,288]
constexpr size_t U_BTG   = U_ABG  + rnd64((size_t)MP * 288);         // [192,288]
constexpr size_t U_BTGCN = U_BTG  + rnd64(192 * 288);                // [192,64]
constexpr size_t U_BTY1  = U_BTGCN+ rnd64(192 * 64);                 // [192,544]
constexpr size_t U_BTY2  = U_BTY1 + rnd64(192 * 544);                // [192,544]
constexpr size_t U_BTS1  = U_BTY2 + rnd64(192 * 544);                // [1024,160]
constexpr size_t U_BTS2  = U_BTS1 + rnd64(1024 * 160);               // [128,1024]

// ---------------- bf16 helpers ----------------
__device__ inline u16 f2bf(float f) {
    u32 u = __float_as_uint(f);
    return (u16)((u + 0x7fffu + ((u >> 16) & 1u)) >> 16);
}
__device__ inline u32 pk2(float a, float b) { return (u32)f2bf(a) | ((u32)f2bf(b) << 16); }
__device__ inline float bflo(u32 w) { return __uint_as_float(w << 16); }
__device__ inline float bfhi(u32 w) { return __uint_as_float(w & 0xffff0000u); }
__device__ inline float bf1(u16 x) { return __uint_as_float((u32)x << 16); }
__device__ inline u32 encf(float x) {
    u32 u = __float_as_uint(x);
    return (u & 0x80000000u) ? ~u : (u | 0x80000000u);
}
__device__ inline float decf(u32 e) {
    u32 u = (e & 0x80000000u) ? (e & 0x7fffffffu) : ~e;
    return __uint_as_float(u);
}
__device__ inline float fexp(float x) { return __expf(x); }

typedef __attribute__((ext_vector_type(8))) short s8b;
typedef __attribute__((ext_vector_type(4))) float f32x4;

// ---------------- CSR build ----------------
__global__ void k_count(const int* __restrict__ ei, const float* __restrict__ ew,
                        int* __restrict__ counts, float* __restrict__ wdeg) {
    int e = blockIdx.x * 256 + threadIdx.x;
    if (e < N_EDGES) {
        int dst = ei[N_EDGES + e];
        atomicAdd(&counts[dst], 1);
        atomicAdd(&wdeg[dst], ew[e]);
    }
}

__global__ __launch_bounds__(256) void k_bsum(const int* __restrict__ counts,
                                              const float* __restrict__ wdeg,
                                              int* __restrict__ bsum,
                                              float* __restrict__ dis) {
    int i = blockIdx.x * 256 + threadIdx.x;
    int v = (i < N_NODES) ? counts[i] : 0;
    if (i < N_NODES) {
        float d = 1.f + wdeg[i];
        dis[i] = (d > 0.f) ? rsqrtf(fmaxf(d, 1e-12f)) : 0.f;
    }
    int x = v;
    #pragma unroll
    for (int off = 1; off < 64; off <<= 1) x += __shfl_xor(x, off);
    __shared__ int ws4[4];
    if ((threadIdx.x & 63) == 0) ws4[threadIdx.x >> 6] = x;
    __syncthreads();
    if (threadIdx.x == 0) bsum[blockIdx.x] = ws4[0] + ws4[1] + ws4[2] + ws4[3];
}

__global__ __launch_bounds__(256) void k_apply(int* __restrict__ counts,
                                               const int* __restrict__ bsum,
                                               int* __restrict__ indptr) {
    __shared__ int s1[4], s2[4];
    const int b = blockIdx.x;
    const int tid = threadIdx.x, lane = tid & 63, w = tid >> 6;
    int part = (tid < b) ? bsum[tid] : 0;
    #pragma unroll
    for (int off = 1; off < 64; off <<= 1) part += __shfl_xor(part, off);
    if (lane == 0) s1[w] = part;
    int i = b * 256 + tid;
    int v = (i < N_NODES) ? counts[i] : 0;
    int x = v;
    #pragma unroll
    for (int off = 1; off < 64; off <<= 1) {
        int y = __shfl_up(x, off);
        if (lane >= off) x += y;
    }
    if (lane == 63) s2[w] = x;
    __syncthreads();
    int add = s1[0] + s1[1] + s1[2] + s1[3];
    for (int k2 = 0; k2 < w; ++k2) add += s2[k2];
    if (i < N_NODES) {
        indptr[i] = add + x - v;
        counts[i] = 0;
    }
    if (i == N_NODES) indptr[N_NODES] = N_EDGES;
}

__global__ void k_scatter(const int* __restrict__ ei, const float* __restrict__ ew,
                          const int* __restrict__ indptr, int* __restrict__ cursor,
                          int* __restrict__ csr_src, float* __restrict__ csr_w) {
    int e = blockIdx.x * 256 + threadIdx.x;
    if (e >= N_EDGES) return;
    int src = ei[e];
    int dst = ei[N_EDGES + e];
    int pos = indptr[dst] + atomicAdd(&cursor[dst], 1);
    csr_src[pos] = src;
    csr_w[pos] = ew[e];
}

// ---------------- merged weight + X conversion + zeroing ----------------
constexpr int S0 = 192 * 288;
constexpr int S1 = 192 * 64;
constexpr int S2 = 192 * 544;
constexpr int S3 = 192 * 544;
constexpr int S4 = 1024 * 160;
constexpr int S5 = 128 * 1024;
constexpr int S6 = N_NODES * 64;
constexpr int S7 = 2 * 8 * HID;
constexpr int S8 = N_NODES + N_NODES + GRAPHS * HID;
constexpr int SW_TOT = S0 + S1 + S2 + S3 + S4 + S5 + S6 + S7 + S8;

__global__ void k_cvtW(const float* __restrict__ Wfc1, const float* __restrict__ Wfc2,
                       const float* __restrict__ Wgcn, const float* __restrict__ Wgat1,
                       const float* __restrict__ Wgat2, const float* __restrict__ Wg1,
                       const float* __restrict__ Wg2, const float* __restrict__ X,
                       const float* __restrict__ as1, const float* __restrict__ ad1,
                       const float* __restrict__ as2, const float* __restrict__ ad2,
                       u16* __restrict__ BTG, u16* __restrict__ BTGCN,
                       u16* __restrict__ BTY1, u16* __restrict__ BTY2,
                       u16* __restrict__ BTS1, u16* __restrict__ BTS2,
                       float* __restrict__ cmp1, float* __restrict__ cmp2,
                       u16* __restrict__ ABX,
                       u32* __restrict__ zc, u32* __restrict__ zw, u32* __restrict__ zg) {
    int idx = blockIdx.x * 256 + threadIdx.x;
    if (idx < S0) {
        int n = idx / 288, k = idx - n * 288;
        u16 v = 0;
        if (n < HID) {
            if (k < HID) v = f2bf(Wfc1[(size_t)k * HID + n]);
            else if (k < 2 * HID) v = f2bf(Wfc2[(size_t)(k - HID) * HID + n]);
        }
        BTG[idx] = v;
        return;
    }
    idx -= S0;
    if (idx < S1) {
        int n = idx / 64, k = idx - n * 64;
        BTGCN[idx] = (k < F_IN && n < HID) ? f2bf(Wgcn[(size_t)k * HID + n]) : (u16)0;
        return;
    }
    idx -= S1;
    if (idx < S2 + S3) {
        int l = (idx >= S2);
        int li = l ? (idx - S2) : idx;
        int n = li / 544, c = li - n * 544;
        int k = c / 136, j = c - k * 136;
        const float* W = l ? Wgat2 : Wgat1;
        u16 v = 0;
        if (n < HID && j < HID) v = f2bf(0.25f * W[(size_t)j * HID4 + k * HID + n]);
        (l ? BTY2 : BTY1)[li] = v;
        return;
    }
    idx -= S2 + S3;
    if (idx < S4) {
        int n = idx / 160, k = idx - n * 160;
        BTS1[idx] = (k < HID) ? f2bf(Wg1[(size_t)k * GFC + n]) : (u16)0;
        return;
    }
    idx -= S4;
    if (idx < S5) {
        int n = idx / 1024, k = idx - n * 1024;
        BTS2[idx] = f2bf(Wg2[(size_t)k * OUT_DIM + n]);
        return;
    }
    idx -= S5;
    if (idx < S6) {
        int r = idx / 64, k = idx - r * 64;
        ABX[idx] = (k < F_IN) ? f2bf(X[(size_t)r * F_IN + k]) : (u16)0;
        return;
    }
    idx -= S6;
    if (idx < S7) {
        int l = idx / (8 * HID); idx -= l * (8 * HID);
        int q = idx / HID;  int c = idx - q * HID;
        int k = q & 3;
        const float* W = l ? Wgat2 : Wgat1;
        const float* a = (q < 4) ? (l ? as2 : as1) : (l ? ad2 : ad1);
        const float* wr = W + (size_t)c * HID4 + k * HID;
        const float* ar = a + k * HID;
        float sum = 0.f;
        for (int cc = 0; cc < HID; ++cc) sum += wr[cc] * ar[cc];
        (l ? cmp2 : cmp1)[q * HID + c] = sum;
        return;
    }
    idx -= S7;
    if (idx < S8) {
        if (idx < N_NODES) zc[idx] = 0;
        else if (idx < 2 * N_NODES) zw[idx - N_NODES] = 0;
        else zg[idx - 2 * N_NODES] = 0;
    }
}

// ---------------- MFMA bf16 GEMM, M-tile 32, NT col-tiles, optional esd ------
template <int NT, bool ESD>
__global__ __launch_bounds__(256) void k_gemm(
    const u16* __restrict__ A, const u16* __restrict__ Bt,
    int M, int N, int Kp,
    float* __restrict__ Cf,
    u16* __restrict__ Cb, int ldcb, int padN,
    u16* __restrict__ Cb2, int ldcb2, int coff2,
    const float* __restrict__ bias, int relu, int gate,
    const float* __restrict__ b2, const float* __restrict__ pb,
    u32* __restrict__ genc,
    const float* __restrict__ compG, float* __restrict__ esdOut) {
    __shared__ float xs[ESD ? 32 : 1][134];
    __shared__ float cmp[ESD ? 8 : 1][132];
    const int bm = blockIdx.x * 32;
    const int w = threadIdx.x >> 6;
    const int lane = threadIdx.x & 63;
    const int m16 = lane & 15;
    const int quad = lane >> 4;
    const u16* Ab = A + (size_t)(bm + m16) * Kp + quad * 8;
    const u16* Bb[NT];
    #pragma unroll
    for (int j = 0; j < NT; ++j)
        Bb[j] = Bt + (size_t)(j * 64 + w * 16 + m16) * Kp + quad * 8;
    f32x4 acc[NT][2];
    #pragma unroll
    for (int j = 0; j < NT; ++j)
        #pragma unroll
        for (int r = 0; r < 2; ++r) acc[j][r] = (f32x4){0.f, 0.f, 0.f, 0.f};
    for (int k0 = 0; k0 < Kp; k0 += 32) {
        s8b a0 = *(const s8b*)(Ab + k0);
        s8b a1 = *(const s8b*)(Ab + (size_t)16 * Kp + k0);
        #pragma unroll
        for (int j = 0; j < NT; ++j) {
            s8b b = *(const s8b*)(Bb[j] + k0);
            acc[j][0] = __builtin_amdgcn_mfma_f32_16x16x32_bf16(a0, b, acc[j][0], 0, 0, 0);
            acc[j][1] = __builtin_amdgcn_mfma_f32_16x16x32_bf16(a1, b, acc[j][1], 0, 0, 0);
        }
    }
    const int g0 = (bm * GRAPHS) / N_NODES;
    int gend = bm + 31; if (gend >= M) gend = M - 1;
    const int g1 = (gend * GRAPHS) / N_NODES;
    #pragma unroll
    for (int j = 0; j < NT; ++j) {
        const int col = j * 64 + w * 16 + m16;
        const bool colok = col < N;
        float bsum = 0.f;
        if (colok) {
            if (gate) bsum = bias[col] + b2[col] + pb[col];
            else if (bias) bsum = bias[col];
        }
        float mx0 = -3.4e38f, mx1 = -3.4e38f;
        #pragma unroll
        for (int r = 0; r < 2; ++r) {
            #pragma unroll
            for (int jj = 0; jj < 4; ++jj) {
                int row = bm + r * 16 + quad * 4 + jj;
                if (row >= M || !colok) continue;
                float v = acc[j][r][jj] + bsum;
                float res;
                if (gate) {
                    float z = 1.f / (1.f + fexp(-v));
                    float xcv = bf1(A[(size_t)row * Kp + col]);
                    float xpv = bf1(A[(size_t)row * Kp + 132 + col]);
                    res = z * xcv + (1.f - z) * xpv;
                } else {
                    if (relu) v = fmaxf(v, 0.f);
                    res = v;
                }
                if constexpr (ESD) {
                    if (col < 132) xs[row - bm][col] = res;
                }
                if (genc) {
                    int gid = (row * GRAPHS) / N_NODES;
                    if (gid == g0) mx0 = fmaxf(mx0, res);
                    else           mx1 = fmaxf(mx1, res);
                }
                if (Cf) Cf[(size_t)row * N + col] = res;
                if (Cb) Cb[(size_t)row * ldcb + col] = f2bf(res);
                if (Cb2) Cb2[(size_t)row * ldcb2 + coff2 + col] = f2bf(res);
            }
        }
        if (genc && colok) {
            mx0 = fmaxf(mx0, __shfl_xor(mx0, 16));
            mx0 = fmaxf(mx0, __shfl_xor(mx0, 32));
            if (g1 != g0) {
                mx1 = fmaxf(mx1, __shfl_xor(mx1, 16));
                mx1 = fmaxf(mx1, __shfl_xor(mx1, 32));
            }
            if (quad == 0) {
                atomicMax(&genc[g0 * HID + col], encf(mx0));
                if (g1 != g0) atomicMax(&genc[g1 * HID + col], encf(mx1));
            }
        }
    }
    if constexpr (ESD) {
        for (int i2 = threadIdx.x; i2 < 8 * HID; i2 += 256)
            cmp[i2 / HID][i2 % HID] = compG[i2];
        __syncthreads();
        int row = threadIdx.x >> 3, q8 = threadIdx.x & 7;
        if (bm + row < M) {
            float s = 0.f;
            for (int c = 0; c < HID; ++c) s += xs[row][c] * cmp[q8][c];
            esdOut[(size_t)(bm + row) * 8 + q8] = s;
        }
    }
}

// ---------------- GCN aggregate in X-domain (33 ch, 2 edges/wave-iter) -------
__global__ __launch_bounds__(256) void k_gcn_aggX(
    const u16* __restrict__ xb, const int* __restrict__ indptr,
    const int* __restrict__ csr_src, const float* __restrict__ csr_w,
    const float* __restrict__ dis, u16* __restrict__ aggx) {
    const int w = threadIdx.x >> 6, t = threadIdx.x & 63;
    const int i = blockIdx.x * 4 + w;
    const int g = t >> 5;
    const int c = t & 31;
    const float di = dis[i];
    const int s = indptr[i], e = indptr[i + 1];
    const u32* X32 = (const u32*)xb;
    float aLo = 0.f, aHi = 0.f;
    int j = s;
    for (; j + 3 < e; j += 4) {
        int j0 = j + g, j1 = j + 2 + g;
        int s0 = csr_src[j0], s1 = csr_src[j1];
        float n0 = dis[s0] * csr_w[j0] * di;
        float n1 = dis[s1] * csr_w[j1] * di;
        u32 v0 = X32[(size_t)s0 * 32 + c];
        u32 v1 = X32[(size_t)s1 * 32 + c];
        aLo += n0 * bflo(v0) + n1 * bflo(v1);
        aHi += n0 * bfhi(v0) + n1 * bfhi(v1);
    }
    for (; j < e; j += 2) {
        int jj = j + g;
        if (jj < e) {
            int s0 = csr_src[jj];
            float n0 = dis[s0] * csr_w[jj] * di;
            u32 v0 = X32[(size_t)s0 * 32 + c];
            aLo += n0 * bflo(v0);
            aHi += n0 * bfhi(v0);
        }
    }
    aLo += __shfl_xor(aLo, 32);
    aHi += __shfl_xor(aHi, 32);
    if (t < 32) {
        float nself = di * di;
        u32 v = X32[(size_t)i * 32 + t];
        aLo += nself * bflo(v);
        aHi += nself * bfhi(v);
        ((u32*)aggx)[(size_t)i * 32 + t] = pk2(aLo, aHi);
    }
}

// ---------------- GAT softmax (no-max, distributed exp) + x-domain aggregate -
__global__ __launch_bounds__(256) void k_gat_node(
    const u16* __restrict__ xt, const float* __restrict__ esd,
    const int* __restrict__ indptr, const int* __restrict__ csr_src,
    float* __restrict__ tmp, u16* __restrict__ y) {
    __shared__ __align__(16) float al[4][CAP * 4];
    __shared__ int srcl[4][CAP];
    const int w = threadIdx.x >> 6, t = threadIdx.x & 63;
    const int i = blockIdx.x * 4 + w;
    const int k = t & 3;
    const int s = indptr[i];
    const int deg = indptr[i + 1] - s;
    const bool fast = (deg <= CAP);
    const float edk = esd[i * 8 + 4 + k];
    float eself = esd[i * 8 + k] + edk;
    eself = (eself >= 0.f) ? eself : 0.2f * eself;
    float dsum = 0.f;
    for (int j0 = 0; j0 < deg; j0 += 16) {
        int j = j0 + (t >> 2);
        if (j < deg) {
            int src = csr_src[s + j];
            float e = esd[src * 8 + k] + edk;
            e = (e >= 0.f) ? e : 0.2f * e;
            float ex = fexp(e);
            if (fast) { al[w][j * 4 + k] = ex; if (k == 0) srcl[w][j] = src; }
            else tmp[(size_t)(s + j) * 4 + k] = ex;
            dsum += ex;
        }
    }
    dsum += __shfl_xor(dsum, 4);
    dsum += __shfl_xor(dsum, 8);
    dsum += __shfl_xor(dsum, 16);
    dsum += __shfl_xor(dsum, 32);
    float exs = fexp(eself);
    dsum += exs;
    float inv = 1.f / dsum;
    float aself = exs * inv;
    float a0 = __shfl(aself, 0), a1 = __shfl(aself, 1);
    float a2 = __shfl(aself, 2), a3 = __shfl(aself, 3);
    if (fast) {
        for (int idx = t; idx < deg * 4; idx += 64) al[w][idx] *= inv;
    }
    const u32* X = (const u32*)xt;   // row stride 80 u32
    float yL0, yH0, yL1, yH1, yL2, yH2, yL3, yH3;
    float zL0 = 0, zH0 = 0, zL1 = 0, zH1 = 0, zL2 = 0, zH2 = 0, zL3 = 0, zH3 = 0;
    {
        u32 v = X[(size_t)i * 80 + t];
        float lo = bflo(v), hi = bfhi(v);
        yL0 = a0 * lo; yH0 = a0 * hi;
        yL1 = a1 * lo; yH1 = a1 * hi;
        yL2 = a2 * lo; yH2 = a2 * hi;
        yL3 = a3 * lo; yH3 = a3 * hi;
        if (t < 2) {
            u32 v2 = X[(size_t)i * 80 + 64 + t];
            float l2 = bflo(v2), h2 = bfhi(v2);
            zL0 = a0 * l2; zH0 = a0 * h2;
            zL1 = a1 * l2; zH1 = a1 * h2;
            zL2 = a2 * l2; zH2 = a2 * h2;
            zL3 = a3 * l2; zH3 = a3 * h2;
        }
    }
    if (fast) {
        int j = 0;
        for (; j + 3 < deg; j += 4) {
            int s0 = srcl[w][j], s1 = srcl[w][j + 1], s2 = srcl[w][j + 2], s3 = srcl[w][j + 3];
            u32 v0 = X[(size_t)s0 * 80 + t];
            u32 v1 = X[(size_t)s1 * 80 + t];
            u32 v2 = X[(size_t)s2 * 80 + t];
            u32 v3 = X[(size_t)s3 * 80 + t];
            float4 x0 = *(const float4*)&al[w][j * 4];
            float4 x1 = *(const float4*)&al[w][j * 4 + 4];
            float4 x2 = *(const float4*)&al[w][j * 4 + 8];
            float4 x3 = *(const float4*)&al[w][j * 4 + 12];
            float l0 = bflo(v0), h0 = bfhi(v0), l1 = bflo(v1), h1 = bfhi(v1);
            float l2 = bflo(v2), h2 = bfhi(v2), l3 = bflo(v3), h3 = bfhi(v3);
            yL0 += x0.x * l0 + x1.x * l1 + x2.x * l2 + x3.x * l3;
            yH0 += x0.x * h0 + x1.x * h1 + x2.x * h2 + x3.x * h3;
            yL1 += x0.y * l0 + x1.y * l1 + x2.y * l2 + x3.y * l3;
            yH1 += x0.y * h0 + x1.y * h1 + x2.y * h2 + x3.y * h3;
            yL2 += x0.z * l0 + x1.z * l1 + x2.z * l2 + x3.z * l3;
            yH2 += x0.z * h0 + x1.z * h1 + x2.z * h2 + x3.z * h3;
            yL3 += x0.w * l0 + x1.w * l1 + x2.w * l2 + x3.w * l3;
            yH3 += x0.w * h0 + x1.w * h1 + x2.w * h2 + x3.w * h3;
            if (t < 2) {
                u32 e0 = X[(size_t)s0 * 80 + 64 + t];
                u32 e1 = X[(size_t)s1 * 80 + 64 + t];
                u32 e2 = X[(size_t)s2 * 80 + 64 + t];
                u32 e3 = X[(size_t)s3 * 80 + 64 + t];
                float el0 = bflo(e0), eh0 = bfhi(e0), el1 = bflo(e1), eh1 = bfhi(e1);
                float el2 = bflo(e2), eh2 = bfhi(e2), el3 = bflo(e3), eh3 = bfhi(e3);
                zL0 += x0.x * el0 + x1.x * el1 + x2.x * el2 + x3.x * el3;
                zH0 += x0.x * eh0 + x1.x * eh1 + x2.x * eh2 + x3.x * eh3;
                zL1 += x0.y * el0 + x1.y * el1 + x2.y * el2 + x3.y * el3;
                zH1 += x0.y * eh0 + x1.y * eh1 + x2.y * eh2 + x3.y * eh3;
                zL2 += x0.z * el0 + x1.z * el1 + x2.z * el2 + x3.z * el3;
                zH2 += x0.z * eh0 + x1.z * eh1 + x2.z * eh2 + x3.z * eh3;
                zL3 += x0.w * el0 + x1.w * el1 + x2.w * el2 + x3.w * el3;
                zH3 += x0.w * eh0 + x1.w * eh1 + x2.w * eh2 + x3.w * eh3;
            }
        }
        for (; j < deg; ++j) {
            int s0 = srcl[w][j];
            u32 v0 = X[(size_t)s0 * 80 + t];
            float4 x0 = *(const float4*)&al[w][j * 4];
            float l0 = bflo(v0), h0 = bfhi(v0);
            yL0 += x0.x * l0; yH0 += x0.x * h0;
            yL1 += x0.y * l0; yH1 += x0.y * h0;
            yL2 += x0.z * l0; yH2 += x0.z * h0;
            yL3 += x0.w * l0; yH3 += x0.w * h0;
            if (t < 2) {
                u32 e0 = X[(size_t)s0 * 80 + 64 + t];
                float el0 = bflo(e0), eh0 = bfhi(e0);
                zL0 += x0.x * el0; zH0 += x0.x * eh0;
                zL1 += x0.y * el0; zH1 += x0.y * eh0;
                zL2 += x0.z * el0; zH2 += x0.z * eh0;
                zL3 += x0.w * el0; zH3 += x0.w * eh0;
            }
        }
    } else {
        float inv0 = __shfl(inv, 0), inv1 = __shfl(inv, 1);
        float inv2 = __shfl(inv, 2), inv3 = __shfl(inv, 3);
        const float4* tmp4 = (const float4*)tmp;
        for (int j = 0; j < deg; ++j) {
            int src = csr_src[s + j];
            float4 ax = tmp4[s + j];
            float b0 = ax.x * inv0, b1 = ax.y * inv1, b2 = ax.z * inv2, b3 = ax.w * inv3;
            u32 v0 = X[(size_t)src * 80 + t];
            float l0 = bflo(v0), h0 = bfhi(v0);
            yL0 += b0 * l0; yH0 += b0 * h0;
            yL1 += b1 * l0; yH1 += b1 * h0;
            yL2 += b2 * l0; yH2 += b2 * h0;
            yL3 += b3 * l0; yH3 += b3 * h0;
            if (t < 2) {
                u32 e0 = X[(size_t)src * 80 + 64 + t];
                float el0 = bflo(e0), eh0 = bfhi(e0);
                zL0 += b0 * el0; zH0 += b0 * eh0;
                zL1 += b1 * el0; zH1 += b1 * eh0;
                zL2 += b2 * el0; zH2 += b2 * eh0;
                zL3 += b3 * el0; zH3 += b3 * eh0;
            }
        }
    }
    u32* yr = (u32*)(y + (size_t)i * YW);
    yr[t]       = pk2(yL0, yH0);
    yr[68 + t]  = pk2(yL1, yH1);
    yr[136 + t] = pk2(yL2, yH2);
    yr[204 + t] = pk2(yL3, yH3);
    if (t < 2) {
        yr[64 + t]  = pk2(zL0, zH0);
        yr[132 + t] = pk2(zL1, zH1);
        yr[200 + t] = pk2(zL2, zH2);
        yr[268 + t] = pk2(zL3, zH3);
    } else if (t < 4) {
        yr[64 + t] = 0; yr[132 + t] = 0; yr[200 + t] = 0; yr[268 + t] = 0;
    }
}

// ---------------- MLP head ----------------
__global__ __launch_bounds__(256) void k_head(
    const u32* __restrict__ genc, const u16* __restrict__ BTS1,
    const u16* __restrict__ BTS2, const float* __restrict__ b_g1,
    const float* __restrict__ b_g2, float* __restrict__ out) {
    __shared__ u32 g_sm[66];
    __shared__ float h_sm[GFC];
    __shared__ float part[OUT_DIM];
    const int g = blockIdx.x;
    const int tid = threadIdx.x;
    if (tid < 66) {
        float a0 = decf(genc[g * HID + 2 * tid]);
        float a1 = decf(genc[g * HID + 2 * tid + 1]);
        g_sm[tid] = pk2(a0, a1);
    }
    __syncthreads();
    #pragma unroll
    for (int r = 0; r < 4; ++r) {
        int o = tid + 256 * r;
        const u32* wr = (const u32*)(BTS1 + (size_t)o * 160);
        float acc = 0.f;
        for (int c = 0; c < 66; ++c) {
            u32 wv = wr[c], gv = g_sm[c];
            acc += bflo(wv) * bflo(gv) + bfhi(wv) * bfhi(gv);
        }
        acc = fmaxf(acc + b_g1[o], 0.f);
        h_sm[o] = __uint_as_float((u32)f2bf(acc) << 16);
    }
    __syncthreads();
    const int o = tid & 127, half = tid >> 7;
    const u32* wr2 = (const u32*)(BTS2 + (size_t)o * 1024 + half * 512);
    const float* hh = h_sm + half * 512;
    float acc = 0.f;
    for (int c = 0; c < 256; ++c) {
        u32 wv = wr2[c];
        acc += bflo(wv) * hh[2 * c] + bfhi(wv) * hh[2 * c + 1];
    }
    if (half == 1) part[o] = acc;
    __syncthreads();
    if (half == 0) out[(size_t)g * OUT_DIM + o] = acc + part[o] + b_g2[o];
}

// ---------------- launch ----------------
extern "C" void kernel_launch(void* const* d_in, const int* in_sizes, int n_in,
                              void* d_out, int out_size, void* d_ws, size_t ws_size,
                              hipStream_t stream) {
    const float* X       = (const float*)d_in[0];
    const int*   EI      = (const int*)d_in[1];
    const float* EW      = (const float*)d_in[2];
    const float* W_gcn   = (const float*)d_in[4];
    const float* b_gcn   = (const float*)d_in[5];
    const float* W_gat1  = (const float*)d_in[6];
    const float* a_src1  = (const float*)d_in[7];
    const float* a_dst1  = (const float*)d_in[8];
    const float* b_gat1  = (const float*)d_in[9];
    const float* W_gat2  = (const float*)d_in[10];
    const float* a_src2  = (const float*)d_in[11];
    const float* a_dst2  = (const float*)d_in[12];
    const float* b_gat2  = (const float*)d_in[13];
    const float* W_fc1   = (const float*)d_in[14];
    const float* b_fc1   = (const float*)d_in[15];
    const float* W_fc2   = (const float*)d_in[16];
    const float* b_fc2   = (const float*)d_in[17];
    const float* pro_bias= (const float*)d_in[18];
    const float* W_g1    = (const float*)d_in[19];
    const float* b_g1    = (const float*)d_in[20];
    const float* W_g2    = (const float*)d_in[21];
    const float* b_g2    = (const float*)d_in[22];
    float* OUT = (float*)d_out;

    float* ws = (float*)d_ws;
    float*    dis     = ws + O_DIS;
    int*      counts  = (int*)(ws + O_CNT);
    float*    wdeg    = ws + O_WDEG;
    int*      indptr  = (int*)(ws + O_IDP);
    int*      bsum    = (int*)(ws + O_BSUM);
    int*      csr_src = (int*)(ws + O_CSR_S);
    float*    csr_w   = ws + O_CSR_W;
    float*    esd     = ws + O_ESD;
    u32*      genc    = (u32*)(ws + O_GE);
    float*    cmp1    = ws + O_CMP1;
    float*    cmp2    = ws + O_CMP2;
    float*    tmp     = ws + O_TMP;
    u16*      U       = (u16*)(ws + O_U);
    u16*      ABX     = U + U_ABX;
    u16*      AGG     = U + U_AGG;
    u16*      y       = U + U_Y;
    u16*      ABF     = U + U_ABF;
    u16*      ABG     = U + U_ABG;
    u16*      BTG     = U + U_BTG;
    u16*      BTGCN   = U + U_BTGCN;
    u16*      BTY1    = U + U_BTY1;
    u16*      BTY2    = U + U_BTY2;
    u16*      BTS1    = U + U_BTS1;
    u16*      BTS2    = U + U_BTS2;

    const int EB = (N_EDGES + 255) / 256;
    const int NB4 = N_NODES / 4;   // 7500
    const int GB_ = MP / 32;       // 938

    // ---- weight/X conversions + zeroing ----
    k_cvtW<<<(SW_TOT + 255) / 256, 256, 0, stream>>>(
        W_fc1, W_fc2, W_gcn, W_gat1, W_gat2, W_g1, W_g2, X,
        a_src1, a_dst1, a_src2, a_dst2,
        BTG, BTGCN, BTY1, BTY2, BTS1, BTS2, cmp1, cmp2, ABX,
        (u32*)counts, (u32*)wdeg, genc);

    // ---- CSR build ----
    k_count<<<EB, 256, 0, stream>>>(EI, EW, counts, wdeg);
    k_bsum<<<NBLK, 256, 0, stream>>>(counts, wdeg, bsum, dis);
    k_apply<<<NBLK, 256, 0, stream>>>(counts, bsum, indptr);
    k_scatter<<<EB, 256, 0, stream>>>(EI, EW, indptr, counts, csr_src, csr_w);

    // ---- GCN: aggregate X-domain, then GEMM (emits x1 -> ABF/ABG + esd1) ----
    k_gcn_aggX<<<NB4, 256, 0, stream>>>(ABX, indptr, csr_src, csr_w, dis, AGG);
    k_gemm<3, true><<<GB_, 256, 0, stream>>>(AGG, BTGCN, N_NODES, HID, 64,
                                             nullptr, ABF, 160, 160, ABG, 288, 132,
                                             b_gcn, 1, 0, nullptr, nullptr, nullptr,
                                             cmp1, esd);

    // ---- GAT layer 1 ----
    k_gat_node<<<NB4, 256, 0, stream>>>(ABF, esd, indptr, csr_src, tmp, y);
    k_gemm<3, false><<<GB_, 256, 0, stream>>>(y, BTY1, N_NODES, HID, YW,
                                              nullptr, ABG, 288, 0, nullptr, 0, 0,
                                              b_gat1, 1, 0, nullptr, nullptr, nullptr,
                                              nullptr, nullptr);
    // gate 1: x2 -> ABF (x-table layer 2) + ABG cols 132.. + esd2
    k_gemm<3, true><<<GB_, 256, 0, stream>>>(ABG, BTG, N_NODES, HID, 288,
                                             nullptr, ABF, 160, 160, ABG, 288, 132,
                                             b_fc1, 0, 1, b_fc2, pro_bias, nullptr,
                                             cmp2, esd);

    // ---- GAT layer 2 ----
    k_gat_node<<<NB4, 256, 0, stream>>>(ABF, esd, indptr, csr_src, tmp, y);
    k_gemm<3, false><<<GB_, 256, 0, stream>>>(y, BTY2, N_NODES, HID, YW,
                                              nullptr, ABG, 288, 0, nullptr, 0, 0,
                                              b_gat2, 0, 0, nullptr, nullptr, nullptr,
                                              nullptr, nullptr);
    // gate 2: pool directly into genc
    k_gemm<3, false><<<GB_, 256, 0, stream>>>(ABG, BTG, N_NODES, HID, 288,
                                              nullptr, nullptr, 0, 0, nullptr, 0, 0,
                                              b_fc1, 0, 1, b_fc2, pro_bias, genc,
                                              nullptr, nullptr);

    // ---- MLP head ----
    k_head<<<GRAPHS, 256, 0, stream>>>(genc, BTS1, BTS2, b_g1, b_g2, OUT);
}

// Round 16
// 363.421 us; speedup vs baseline: 1.3263x; 1.0753x over previous
//
#include <hip/hip_runtime.h>

// ---------------- problem constants ----------------
constexpr int N_NODES = 30000;
constexpr int N_EDGES = 300000;
constexpr int GRAPHS  = 64;
constexpr int F_IN    = 33;
constexpr int HID     = 132;
constexpr int HID4    = 528;
constexpr int OUT_DIM = 128;
constexpr int GFC     = 1024;
constexpr int MP      = 30016;
constexpr int CAP     = 128;
constexpr int NBLK    = 118;           // ceil(N_NODES/256)
constexpr int YW      = 544;           // y row stride u16

typedef unsigned int u32;
typedef unsigned short u16;

// ---------------- workspace layout ----------------
constexpr size_t rnd64(size_t x) { return (x + 63) & ~(size_t)63; }
constexpr size_t O_DIS   = 0;
constexpr size_t O_CNT   = O_DIS   + rnd64(N_NODES);
constexpr size_t O_WDEG  = O_CNT   + rnd64(N_NODES);
constexpr size_t O_IDP   = O_WDEG  + rnd64(N_NODES);
constexpr size_t O_BSUM  = O_IDP   + rnd64(N_NODES + 1);
constexpr size_t O_CSR_S = O_BSUM  + rnd64(128);
constexpr size_t O_CSR_W = O_CSR_S + rnd64(N_EDGES);
constexpr size_t O_ESD   = O_CSR_W + rnd64(N_EDGES);                 // float, N*8
constexpr size_t O_GE    = O_ESD   + rnd64((size_t)N_NODES * 8);     // u32, G*HID
constexpr size_t O_CMP1  = O_GE    + rnd64(GRAPHS * HID);            // float, 8*132
constexpr size_t O_CMP2  = O_CMP1  + rnd64(8 * HID);
constexpr size_t O_TMP   = O_CMP2  + rnd64(8 * HID);                 // float, E*4
// u16 region
constexpr size_t O_U     = O_TMP   + rnd64((size_t)N_EDGES * 4);
constexpr size_t U_ABX   = 0;                                        // [MP,64] X bf16
constexpr size_t U_AGG   = U_ABX  + rnd64((size_t)MP * 64);          // [MP,64] aggX
constexpr size_t U_Y     = U_AGG  + rnd64((size_t)MP * 64);          // [MP,YW]
constexpr size_t U_ABF   = U_Y    + rnd64((size_t)MP * YW);          // [MP,160] x table
constexpr size_t U_ABG   = U_ABF  + rnd64((size_t)MP * 160);         // [MP,288]
constexpr size_t U_BTG   = U_ABG  + rnd64((size_t)MP * 288);         // [192,288]
constexpr size_t U_BTGCN = U_BTG  + rnd64(192 * 288);                // [192,64]
constexpr size_t U_BTY1  = U_BTGCN+ rnd64(192 * 64);                 // [192,544]
constexpr size_t U_BTY2  = U_BTY1 + rnd64(192 * 544);                // [192,544]
constexpr size_t U_BTS1  = U_BTY2 + rnd64(192 * 544);                // [1024,160]
constexpr size_t U_BTS2  = U_BTS1 + rnd64(1024 * 160);               // [128,1024]

// ---------------- bf16 helpers ----------------
__device__ inline u16 f2bf(float f) {
    u32 u = __float_as_uint(f);
    return (u16)((u + 0x7fffu + ((u >> 16) & 1u)) >> 16);
}
__device__ inline u32 pk2(float a, float b) { return (u32)f2bf(a) | ((u32)f2bf(b) << 16); }
__device__ inline float bflo(u32 w) { return __uint_as_float(w << 16); }
__device__ inline float bfhi(u32 w) { return __uint_as_float(w & 0xffff0000u); }
__device__ inline float bf1(u16 x) { return __uint_as_float((u32)x << 16); }
__device__ inline u32 encf(float x) {
    u32 u = __float_as_uint(x);
    return (u & 0x80000000u) ? ~u : (u | 0x80000000u);
}
__device__ inline float decf(u32 e) {
    u32 u = (e & 0x80000000u) ? (e & 0x7fffffffu) : ~e;
    return __uint_as_float(u);
}
__device__ inline float fexp(float x) { return __expf(x); }

typedef __attribute__((ext_vector_type(8))) short s8b;
typedef __attribute__((ext_vector_type(4))) float f32x4;

// ---------------- CSR build ----------------
__global__ void k_count(const int* __restrict__ ei, const float* __restrict__ ew,
                        int* __restrict__ counts, float* __restrict__ wdeg) {
    int e = blockIdx.x * 256 + threadIdx.x;
    if (e < N_EDGES) {
        int dst = ei[N_EDGES + e];
        atomicAdd(&counts[dst], 1);
        atomicAdd(&wdeg[dst], ew[e]);
    }
}

__global__ __launch_bounds__(256) void k_bsum(const int* __restrict__ counts,
                                              const float* __restrict__ wdeg,
                                              int* __restrict__ bsum,
                                              float* __restrict__ dis) {
    int i = blockIdx.x * 256 + threadIdx.x;
    int v = (i < N_NODES) ? counts[i] : 0;
    if (i < N_NODES) {
        float d = 1.f + wdeg[i];
        dis[i] = (d > 0.f) ? rsqrtf(fmaxf(d, 1e-12f)) : 0.f;
    }
    int x = v;
    #pragma unroll
    for (int off = 1; off < 64; off <<= 1) x += __shfl_xor(x, off);
    __shared__ int ws4[4];
    if ((threadIdx.x & 63) == 0) ws4[threadIdx.x >> 6] = x;
    __syncthreads();
    if (threadIdx.x == 0) bsum[blockIdx.x] = ws4[0] + ws4[1] + ws4[2] + ws4[3];
}

__global__ __launch_bounds__(256) void k_apply(int* __restrict__ counts,
                                               const int* __restrict__ bsum,
                                               int* __restrict__ indptr) {
    __shared__ int s1[4], s2[4];
    const int b = blockIdx.x;
    const int tid = threadIdx.x, lane = tid & 63, w = tid >> 6;
    int part = (tid < b) ? bsum[tid] : 0;
    #pragma unroll
    for (int off = 1; off < 64; off <<= 1) part += __shfl_xor(part, off);
    if (lane == 0) s1[w] = part;
    int i = b * 256 + tid;
    int v = (i < N_NODES) ? counts[i] : 0;
    int x = v;
    #pragma unroll
    for (int off = 1; off < 64; off <<= 1) {
        int y = __shfl_up(x, off);
        if (lane >= off) x += y;
    }
    if (lane == 63) s2[w] = x;
    __syncthreads();
    int add = s1[0] + s1[1] + s1[2] + s1[3];
    for (int k2 = 0; k2 < w; ++k2) add += s2[k2];
    if (i < N_NODES) {
        indptr[i] = add + x - v;
        counts[i] = 0;
    }
    if (i == N_NODES) indptr[N_NODES] = N_EDGES;
}

__global__ void k_scatter(const int* __restrict__ ei, const float* __restrict__ ew,
                          const int* __restrict__ indptr, int* __restrict__ cursor,
                          int* __restrict__ csr_src, float* __restrict__ csr_w) {
    int e = blockIdx.x * 256 + threadIdx.x;
    if (e >= N_EDGES) return;
    int src = ei[e];
    int dst = ei[N_EDGES + e];
    int pos = indptr[dst] + atomicAdd(&cursor[dst], 1);
    csr_src[pos] = src;
    csr_w[pos] = ew[e];
}

// ---------------- merged weight + X conversion + zeroing ----------------
constexpr int S0 = 192 * 288;
constexpr int S1 = 192 * 64;
constexpr int S2 = 192 * 544;
constexpr int S3 = 192 * 544;
constexpr int S4 = 1024 * 160;
constexpr int S5 = 128 * 1024;
constexpr int S6 = N_NODES * 64;
constexpr int S7 = 2 * 8 * HID;
constexpr int S8 = N_NODES + N_NODES + GRAPHS * HID;
constexpr int SW_TOT = S0 + S1 + S2 + S3 + S4 + S5 + S6 + S7 + S8;

__global__ void k_cvtW(const float* __restrict__ Wfc1, const float* __restrict__ Wfc2,
                       const float* __restrict__ Wgcn, const float* __restrict__ Wgat1,
                       const float* __restrict__ Wgat2, const float* __restrict__ Wg1,
                       const float* __restrict__ Wg2, const float* __restrict__ X,
                       const float* __restrict__ as1, const float* __restrict__ ad1,
                       const float* __restrict__ as2, const float* __restrict__ ad2,
                       u16* __restrict__ BTG, u16* __restrict__ BTGCN,
                       u16* __restrict__ BTY1, u16* __restrict__ BTY2,
                       u16* __restrict__ BTS1, u16* __restrict__ BTS2,
                       float* __restrict__ cmp1, float* __restrict__ cmp2,
                       u16* __restrict__ ABX,
                       u32* __restrict__ zc, u32* __restrict__ zw, u32* __restrict__ zg) {
    int idx = blockIdx.x * 256 + threadIdx.x;
    if (idx < S0) {
        int n = idx / 288, k = idx - n * 288;
        u16 v = 0;
        if (n < HID) {
            if (k < HID) v = f2bf(Wfc1[(size_t)k * HID + n]);
            else if (k < 2 * HID) v = f2bf(Wfc2[(size_t)(k - HID) * HID + n]);
        }
        BTG[idx] = v;
        return;
    }
    idx -= S0;
    if (idx < S1) {
        int n = idx / 64, k = idx - n * 64;
        BTGCN[idx] = (k < F_IN && n < HID) ? f2bf(Wgcn[(size_t)k * HID + n]) : (u16)0;
        return;
    }
    idx -= S1;
    if (idx < S2 + S3) {
        int l = (idx >= S2);
        int li = l ? (idx - S2) : idx;
        int n = li / 544, c = li - n * 544;
        int k = c / 136, j = c - k * 136;
        const float* W = l ? Wgat2 : Wgat1;
        u16 v = 0;
        if (n < HID && j < HID) v = f2bf(0.25f * W[(size_t)j * HID4 + k * HID + n]);
        (l ? BTY2 : BTY1)[li] = v;
        return;
    }
    idx -= S2 + S3;
    if (idx < S4) {
        int n = idx / 160, k = idx - n * 160;
        BTS1[idx] = (k < HID) ? f2bf(Wg1[(size_t)k * GFC + n]) : (u16)0;
        return;
    }
    idx -= S4;
    if (idx < S5) {
        int n = idx / 1024, k = idx - n * 1024;
        BTS2[idx] = f2bf(Wg2[(size_t)k * OUT_DIM + n]);
        return;
    }
    idx -= S5;
    if (idx < S6) {
        int r = idx / 64, k = idx - r * 64;
        ABX[idx] = (k < F_IN) ? f2bf(X[(size_t)r * F_IN + k]) : (u16)0;
        return;
    }
    idx -= S6;
    if (idx < S7) {
        int l = idx / (8 * HID); idx -= l * (8 * HID);
        int q = idx / HID;  int c = idx - q * HID;
        int k = q & 3;
        const float* W = l ? Wgat2 : Wgat1;
        const float* a = (q < 4) ? (l ? as2 : as1) : (l ? ad2 : ad1);
        const float* wr = W + (size_t)c * HID4 + k * HID;
        const float* ar = a + k * HID;
        float sum = 0.f;
        for (int cc = 0; cc < HID; ++cc) sum += wr[cc] * ar[cc];
        (l ? cmp2 : cmp1)[q * HID + c] = sum;
        return;
    }
    idx -= S7;
    if (idx < S8) {
        if (idx < N_NODES) zc[idx] = 0;
        else if (idx < 2 * N_NODES) zw[idx - N_NODES] = 0;
        else zg[idx - 2 * N_NODES] = 0;
    }
}

// ---------------- MFMA bf16 GEMM, M-tile 32 (GCN layer, fused esd) ----------
template <int NT, bool ESD>
__global__ __launch_bounds__(256) void k_gemm(
    const u16* __restrict__ A, const u16* __restrict__ Bt,
    int M, int N, int Kp,
    float* __restrict__ Cf,
    u16* __restrict__ Cb, int ldcb, int padN,
    u16* __restrict__ Cb2, int ldcb2, int coff2,
    const float* __restrict__ bias, int relu, int gate,
    const float* __restrict__ b2, const float* __restrict__ pb,
    u32* __restrict__ genc,
    const float* __restrict__ compG, float* __restrict__ esdOut) {
    __shared__ float xs[ESD ? 32 : 1][134];
    __shared__ float cmp[ESD ? 8 : 1][132];
    const int bm = blockIdx.x * 32;
    const int w = threadIdx.x >> 6;
    const int lane = threadIdx.x & 63;
    const int m16 = lane & 15;
    const int quad = lane >> 4;
    const u16* Ab = A + (size_t)(bm + m16) * Kp + quad * 8;
    const u16* Bb[NT];
    #pragma unroll
    for (int j = 0; j < NT; ++j)
        Bb[j] = Bt + (size_t)(j * 64 + w * 16 + m16) * Kp + quad * 8;
    f32x4 acc[NT][2];
    #pragma unroll
    for (int j = 0; j < NT; ++j)
        #pragma unroll
        for (int r = 0; r < 2; ++r) acc[j][r] = (f32x4){0.f, 0.f, 0.f, 0.f};
    for (int k0 = 0; k0 < Kp; k0 += 32) {
        s8b a0 = *(const s8b*)(Ab + k0);
        s8b a1 = *(const s8b*)(Ab + (size_t)16 * Kp + k0);
        #pragma unroll
        for (int j = 0; j < NT; ++j) {
            s8b b = *(const s8b*)(Bb[j] + k0);
            acc[j][0] = __builtin_amdgcn_mfma_f32_16x16x32_bf16(a0, b, acc[j][0], 0, 0, 0);
            acc[j][1] = __builtin_amdgcn_mfma_f32_16x16x32_bf16(a1, b, acc[j][1], 0, 0, 0);
        }
    }
    const int g0 = (bm * GRAPHS) / N_NODES;
    int gend = bm + 31; if (gend >= M) gend = M - 1;
    const int g1 = (gend * GRAPHS) / N_NODES;
    #pragma unroll
    for (int j = 0; j < NT; ++j) {
        const int col = j * 64 + w * 16 + m16;
        const bool colok = col < N;
        float bsum = 0.f;
        if (colok) {
            if (gate) bsum = bias[col] + b2[col] + pb[col];
            else if (bias) bsum = bias[col];
        }
        float mx0 = -3.4e38f, mx1 = -3.4e38f;
        #pragma unroll
        for (int r = 0; r < 2; ++r) {
            #pragma unroll
            for (int jj = 0; jj < 4; ++jj) {
                int row = bm + r * 16 + quad * 4 + jj;
                if (row >= M || !colok) continue;
                float v = acc[j][r][jj] + bsum;
                float res;
                if (gate) {
                    float z = 1.f / (1.f + fexp(-v));
                    float xcv = bf1(A[(size_t)row * Kp + col]);
                    float xpv = bf1(A[(size_t)row * Kp + 132 + col]);
                    res = z * xcv + (1.f - z) * xpv;
                } else {
                    if (relu) v = fmaxf(v, 0.f);
                    res = v;
                }
                if constexpr (ESD) {
                    if (col < 132) xs[row - bm][col] = res;
                }
                if (genc) {
                    int gid = (row * GRAPHS) / N_NODES;
                    if (gid == g0) mx0 = fmaxf(mx0, res);
                    else           mx1 = fmaxf(mx1, res);
                }
                if (Cf) Cf[(size_t)row * N + col] = res;
                if (Cb) Cb[(size_t)row * ldcb + col] = f2bf(res);
                if (Cb2) Cb2[(size_t)row * ldcb2 + coff2 + col] = f2bf(res);
            }
        }
        if (genc && colok) {
            mx0 = fmaxf(mx0, __shfl_xor(mx0, 16));
            mx0 = fmaxf(mx0, __shfl_xor(mx0, 32));
            if (g1 != g0) {
                mx1 = fmaxf(mx1, __shfl_xor(mx1, 16));
                mx1 = fmaxf(mx1, __shfl_xor(mx1, 32));
            }
            if (quad == 0) {
                atomicMax(&genc[g0 * HID + col], encf(mx0));
                if (g1 != g0) atomicMax(&genc[g1 * HID + col], encf(mx1));
            }
        }
    }
    if constexpr (ESD) {
        for (int i2 = threadIdx.x; i2 < 8 * HID; i2 += 256)
            cmp[i2 / HID][i2 % HID] = compG[i2];
        __syncthreads();
        int row = threadIdx.x >> 3, q8 = threadIdx.x & 7;
        if (bm + row < M) {
            float s = 0.f;
            for (int c = 0; c < HID; ++c) s += xs[row][c] * cmp[q8][c];
            esdOut[(size_t)(bm + row) * 8 + q8] = s;
        }
    }
}

// ---------------- fused GAT-projection + gate kernel (two-stage MFMA) --------
// Stage A: xc = act(y @ BTY + bgat), staged bf16 into LDS A2 cols 0..131 (and
//          kept fp32 in acc1).  xp loaded into A2 cols 132..263, pad zeroed.
// Stage B: pre = A2 @ BTG; z = sigmoid(pre + biases); res = z*xc + (1-z)*xp.
// L2=false: res -> ABF + ABG cols 132.. + esd (cmp dots).  L2=true: pool genc.
template <bool L2>
__global__ __launch_bounds__(256) void k_fused(
    const u16* __restrict__ yv, const u16* __restrict__ BTY,
    const u16* __restrict__ BTGm, u16* __restrict__ ABG,
    u16* __restrict__ ABF,
    const float* __restrict__ bgat,
    const float* __restrict__ bfc1, const float* __restrict__ bfc2,
    const float* __restrict__ pb,
    const float* __restrict__ compG, float* __restrict__ esdOut,
    u32* __restrict__ genc, int M) {
    __shared__ u16 a2[32 * 288];
    __shared__ float xs[L2 ? 1 : 32][134];
    __shared__ float cmp[L2 ? 1 : 8][132];
    const int bm = blockIdx.x * 32;
    const int w = threadIdx.x >> 6;
    const int lane = threadIdx.x & 63;
    const int m16 = lane & 15;
    const int quad = lane >> 4;
    // xp + pad into A2 cols 132..287 (independent of stage A)
    u32* a2u = (u32*)a2;
    for (int idx = threadIdx.x; idx < 32 * 78; idx += 256) {
        int row = idx / 78, c = idx - row * 78;
        u32 v = 0;
        if (c < 66 && bm + row < M)
            v = ((const u32*)ABG)[(size_t)(bm + row) * 144 + 66 + c];
        a2u[row * 144 + 66 + c] = v;
    }
    // ---- stage A ----
    const u16* Ab = yv + (size_t)(bm + m16) * YW + quad * 8;
    const u16* Bb[3];
    #pragma unroll
    for (int j = 0; j < 3; ++j)
        Bb[j] = BTY + (size_t)(j * 64 + w * 16 + m16) * YW + quad * 8;
    f32x4 acc1[3][2];
    #pragma unroll
    for (int j = 0; j < 3; ++j)
        #pragma unroll
        for (int r = 0; r < 2; ++r) acc1[j][r] = (f32x4){0.f, 0.f, 0.f, 0.f};
    for (int k0 = 0; k0 < YW; k0 += 32) {
        s8b a0 = *(const s8b*)(Ab + k0);
        s8b a1 = *(const s8b*)(Ab + (size_t)16 * YW + k0);
        #pragma unroll
        for (int j = 0; j < 3; ++j) {
            s8b b = *(const s8b*)(Bb[j] + k0);
            acc1[j][0] = __builtin_amdgcn_mfma_f32_16x16x32_bf16(a0, b, acc1[j][0], 0, 0, 0);
            acc1[j][1] = __builtin_amdgcn_mfma_f32_16x16x32_bf16(a1, b, acc1[j][1], 0, 0, 0);
        }
    }
    #pragma unroll
    for (int j = 0; j < 3; ++j) {
        const int col = j * 64 + w * 16 + m16;
        if (col >= HID) continue;
        const float bc = bgat[col];
        #pragma unroll
        for (int r = 0; r < 2; ++r) {
            #pragma unroll
            for (int jj = 0; jj < 4; ++jj) {
                int row = bm + r * 16 + quad * 4 + jj;
                float v = acc1[j][r][jj] + bc;
                if (!L2) v = fmaxf(v, 0.f);
                acc1[j][r][jj] = v;
                if (row < M) a2[(row - bm) * 288 + col] = f2bf(v);
            }
        }
    }
    __syncthreads();
    // ---- stage B ----
    const u16* A2b = a2 + m16 * 288 + quad * 8;
    const u16* Bg[3];
    #pragma unroll
    for (int j = 0; j < 3; ++j)
        Bg[j] = BTGm + (size_t)(j * 64 + w * 16 + m16) * 288 + quad * 8;
    f32x4 acc2[3][2];
    #pragma unroll
    for (int j = 0; j < 3; ++j)
        #pragma unroll
        for (int r = 0; r < 2; ++r) acc2[j][r] = (f32x4){0.f, 0.f, 0.f, 0.f};
    for (int k0 = 0; k0 < 288; k0 += 32) {
        s8b a0 = *(const s8b*)(A2b + k0);
        s8b a1 = *(const s8b*)(A2b + 16 * 288 + k0);
        #pragma unroll
        for (int j = 0; j < 3; ++j) {
            s8b b = *(const s8b*)(Bg[j] + k0);
            acc2[j][0] = __builtin_amdgcn_mfma_f32_16x16x32_bf16(a0, b, acc2[j][0], 0, 0, 0);
            acc2[j][1] = __builtin_amdgcn_mfma_f32_16x16x32_bf16(a1, b, acc2[j][1], 0, 0, 0);
        }
    }
    const int g0 = (bm * GRAPHS) / N_NODES;
    int gend = bm + 31; if (gend >= M) gend = M - 1;
    const int g1 = (gend * GRAPHS) / N_NODES;
    #pragma unroll
    for (int j = 0; j < 3; ++j) {
        const int col = j * 64 + w * 16 + m16;
        const bool colok = col < HID;
        float bsum = colok ? (bfc1[col] + bfc2[col] + pb[col]) : 0.f;
        float mx0 = -3.4e38f, mx1 = -3.4e38f;
        #pragma unroll
        for (int r = 0; r < 2; ++r) {
            #pragma unroll
            for (int jj = 0; jj < 4; ++jj) {
                int row = bm + r * 16 + quad * 4 + jj;
                if (row >= M || !colok) continue;
                float pre = acc2[j][r][jj] + bsum;
                float z = 1.f / (1.f + fexp(-pre));
                float xcv = acc1[j][r][jj];
                float xpv = bf1(a2[(row - bm) * 288 + 132 + col]);
                float res = z * xcv + (1.f - z) * xpv;
                if (!L2) {
                    ABF[(size_t)row * 160 + col] = f2bf(res);
                    ABG[(size_t)row * 288 + 132 + col] = f2bf(res);
                    xs[row - bm][col] = res;
                } else {
                    int gid = (row * GRAPHS) / N_NODES;
                    if (gid == g0) mx0 = fmaxf(mx0, res);
                    else           mx1 = fmaxf(mx1, res);
                }
            }
        }
        if (L2 && colok) {
            mx0 = fmaxf(mx0, __shfl_xor(mx0, 16));
            mx0 = fmaxf(mx0, __shfl_xor(mx0, 32));
            if (g1 != g0) {
                mx1 = fmaxf(mx1, __shfl_xor(mx1, 16));
                mx1 = fmaxf(mx1, __shfl_xor(mx1, 32));
            }
            if (quad == 0) {
                atomicMax(&genc[g0 * HID + col], encf(mx0));
                if (g1 != g0) atomicMax(&genc[g1 * HID + col], encf(mx1));
            }
        }
    }
    if constexpr (!L2) {
        for (int i2 = threadIdx.x; i2 < 8 * HID; i2 += 256)
            cmp[i2 / HID][i2 % HID] = compG[i2];
        __syncthreads();
        int row = threadIdx.x >> 3, q8 = threadIdx.x & 7;
        if (bm + row < M) {
            float s = 0.f;
            for (int c = 0; c < HID; ++c) s += xs[row][c] * cmp[q8][c];
            esdOut[(size_t)(bm + row) * 8 + q8] = s;
        }
    }
}

// ---------------- GCN aggregate in X-domain (33 ch, 2 edges/wave-iter) -------
__global__ __launch_bounds__(256) void k_gcn_aggX(
    const u16* __restrict__ xb, const int* __restrict__ indptr,
    const int* __restrict__ csr_src, const float* __restrict__ csr_w,
    const float* __restrict__ dis, u16* __restrict__ aggx) {
    const int w = threadIdx.x >> 6, t = threadIdx.x & 63;
    const int i = blockIdx.x * 4 + w;
    const int g = t >> 5;
    const int c = t & 31;
    const float di = dis[i];
    const int s = indptr[i], e = indptr[i + 1];
    const u32* X32 = (const u32*)xb;
    float aLo = 0.f, aHi = 0.f;
    int j = s;
    for (; j + 3 < e; j += 4) {
        int j0 = j + g, j1 = j + 2 + g;
        int s0 = csr_src[j0], s1 = csr_src[j1];
        float n0 = dis[s0] * csr_w[j0] * di;
        float n1 = dis[s1] * csr_w[j1] * di;
        u32 v0 = X32[(size_t)s0 * 32 + c];
        u32 v1 = X32[(size_t)s1 * 32 + c];
        aLo += n0 * bflo(v0) + n1 * bflo(v1);
        aHi += n0 * bfhi(v0) + n1 * bfhi(v1);
    }
    for (; j < e; j += 2) {
        int jj = j + g;
        if (jj < e) {
            int s0 = csr_src[jj];
            float n0 = dis[s0] * csr_w[jj] * di;
            u32 v0 = X32[(size_t)s0 * 32 + c];
            aLo += n0 * bflo(v0);
            aHi += n0 * bfhi(v0);
        }
    }
    aLo += __shfl_xor(aLo, 32);
    aHi += __shfl_xor(aHi, 32);
    if (t < 32) {
        float nself = di * di;
        u32 v = X32[(size_t)i * 32 + t];
        aLo += nself * bflo(v);
        aHi += nself * bfhi(v);
        ((u32*)aggx)[(size_t)i * 32 + t] = pk2(aLo, aHi);
    }
}

// ---------------- GAT softmax (no-max, distributed exp) + x-domain aggregate -
__global__ __launch_bounds__(256) void k_gat_node(
    const u16* __restrict__ xt, const float* __restrict__ esd,
    const int* __restrict__ indptr, const int* __restrict__ csr_src,
    float* __restrict__ tmp, u16* __restrict__ y) {
    __shared__ __align__(16) float al[4][CAP * 4];
    __shared__ int srcl[4][CAP];
    const int w = threadIdx.x >> 6, t = threadIdx.x & 63;
    const int i = blockIdx.x * 4 + w;
    const int k = t & 3;
    const int s = indptr[i];
    const int deg = indptr[i + 1] - s;
    const bool fast = (deg <= CAP);
    const float edk = esd[i * 8 + 4 + k];
    float eself = esd[i * 8 + k] + edk;
    eself = (eself >= 0.f) ? eself : 0.2f * eself;
    float dsum = 0.f;
    for (int j0 = 0; j0 < deg; j0 += 16) {
        int j = j0 + (t >> 2);
        if (j < deg) {
            int src = csr_src[s + j];
            float e = esd[src * 8 + k] + edk;
            e = (e >= 0.f) ? e : 0.2f * e;
            float ex = fexp(e);
            if (fast) { al[w][j * 4 + k] = ex; if (k == 0) srcl[w][j] = src; }
            else tmp[(size_t)(s + j) * 4 + k] = ex;
            dsum += ex;
        }
    }
    dsum += __shfl_xor(dsum, 4);
    dsum += __shfl_xor(dsum, 8);
    dsum += __shfl_xor(dsum, 16);
    dsum += __shfl_xor(dsum, 32);
    float exs = fexp(eself);
    dsum += exs;
    float inv = 1.f / dsum;
    float aself = exs * inv;
    float a0 = __shfl(aself, 0), a1 = __shfl(aself, 1);
    float a2 = __shfl(aself, 2), a3 = __shfl(aself, 3);
    if (fast) {
        for (int idx = t; idx < deg * 4; idx += 64) al[w][idx] *= inv;
    }
    const u32* X = (const u32*)xt;   // row stride 80 u32
    float yL0, yH0, yL1, yH1, yL2, yH2, yL3, yH3;
    float zL0 = 0, zH0 = 0, zL1 = 0, zH1 = 0, zL2 = 0, zH2 = 0, zL3 = 0, zH3 = 0;
    {
        u32 v = X[(size_t)i * 80 + t];
        float lo = bflo(v), hi = bfhi(v);
        yL0 = a0 * lo; yH0 = a0 * hi;
        yL1 = a1 * lo; yH1 = a1 * hi;
        yL2 = a2 * lo; yH2 = a2 * hi;
        yL3 = a3 * lo; yH3 = a3 * hi;
        if (t < 2) {
            u32 v2 = X[(size_t)i * 80 + 64 + t];
            float l2 = bflo(v2), h2 = bfhi(v2);
            zL0 = a0 * l2; zH0 = a0 * h2;
            zL1 = a1 * l2; zH1 = a1 * h2;
            zL2 = a2 * l2; zH2 = a2 * h2;
            zL3 = a3 * l2; zH3 = a3 * h2;
        }
    }
    if (fast) {
        int j = 0;
        for (; j + 3 < deg; j += 4) {
            int s0 = srcl[w][j], s1 = srcl[w][j + 1], s2 = srcl[w][j + 2], s3 = srcl[w][j + 3];
            u32 v0 = X[(size_t)s0 * 80 + t];
            u32 v1 = X[(size_t)s1 * 80 + t];
            u32 v2 = X[(size_t)s2 * 80 + t];
            u32 v3 = X[(size_t)s3 * 80 + t];
            float4 x0 = *(const float4*)&al[w][j * 4];
            float4 x1 = *(const float4*)&al[w][j * 4 + 4];
            float4 x2 = *(const float4*)&al[w][j * 4 + 8];
            float4 x3 = *(const float4*)&al[w][j * 4 + 12];
            float l0 = bflo(v0), h0 = bfhi(v0), l1 = bflo(v1), h1 = bfhi(v1);
            float l2 = bflo(v2), h2 = bfhi(v2), l3 = bflo(v3), h3 = bfhi(v3);
            yL0 += x0.x * l0 + x1.x * l1 + x2.x * l2 + x3.x * l3;
            yH0 += x0.x * h0 + x1.x * h1 + x2.x * h2 + x3.x * h3;
            yL1 += x0.y * l0 + x1.y * l1 + x2.y * l2 + x3.y * l3;
            yH1 += x0.y * h0 + x1.y * h1 + x2.y * h2 + x3.y * h3;
            yL2 += x0.z * l0 + x1.z * l1 + x2.z * l2 + x3.z * l3;
            yH2 += x0.z * h0 + x1.z * h1 + x2.z * h2 + x3.z * h3;
            yL3 += x0.w * l0 + x1.w * l1 + x2.w * l2 + x3.w * l3;
            yH3 += x0.w * h0 + x1.w * h1 + x2.w * h2 + x3.w * h3;
            if (t < 2) {
                u32 e0 = X[(size_t)s0 * 80 + 64 + t];
                u32 e1 = X[(size_t)s1 * 80 + 64 + t];
                u32 e2 = X[(size_t)s2 * 80 + 64 + t];
                u32 e3 = X[(size_t)s3 * 80 + 64 + t];
                float el0 = bflo(e0), eh0 = bfhi(e0), el1 = bflo(e1), eh1 = bfhi(e1);
                float el2 = bflo(e2), eh2 = bfhi(e2), el3 = bflo(e3), eh3 = bfhi(e3);
                zL0 += x0.x * el0 + x1.x * el1 + x2.x * el2 + x3.x * el3;
                zH0 += x0.x * eh0 + x1.x * eh1 + x2.x * eh2 + x3.x * eh3;
                zL1 += x0.y * el0 + x1.y * el1 + x2.y * el2 + x3.y * el3;
                zH1 += x0.y * eh0 + x1.y * eh1 + x2.y * eh2 + x3.y * eh3;
                zL2 += x0.z * el0 + x1.z * el1 + x2.z * el2 + x3.z * el3;
                zH2 += x0.z * eh0 + x1.z * eh1 + x2.z * eh2 + x3.z * eh3;
                zL3 += x0.w * el0 + x1.w * el1 + x2.w * el2 + x3.w * el3;
                zH3 += x0.w * eh0 + x1.w * eh1 + x2.w * eh2 + x3.w * eh3;
            }
        }
        for (; j < deg; ++j) {
            int s0 = srcl[w][j];
            u32 v0 = X[(size_t)s0 * 80 + t];
            float4 x0 = *(const float4*)&al[w][j * 4];
            float l0 = bflo(v0), h0 = bfhi(v0);
            yL0 += x0.x * l0; yH0 += x0.x * h0;
            yL1 += x0.y * l0; yH1 += x0.y * h0;
            yL2 += x0.z * l0; yH2 += x0.z * h0;
            yL3 += x0.w * l0; yH3 += x0.w * h0;
            if (t < 2) {
                u32 e0 = X[(size_t)s0 * 80 + 64 + t];
                float el0 = bflo(e0), eh0 = bfhi(e0);
                zL0 += x0.x * el0; zH0 += x0.x * eh0;
                zL1 += x0.y * el0; zH1 += x0.y * eh0;
                zL2 += x0.z * el0; zH2 += x0.z * eh0;
                zL3 += x0.w * el0; zH3 += x0.w * eh0;
            }
        }
    } else {
        float inv0 = __shfl(inv, 0), inv1 = __shfl(inv, 1);
        float inv2 = __shfl(inv, 2), inv3 = __shfl(inv, 3);
        const float4* tmp4 = (const float4*)tmp;
        for (int j = 0; j < deg; ++j) {
            int src = csr_src[s + j];
            float4 ax = tmp4[s + j];
            float b0 = ax.x * inv0, b1 = ax.y * inv1, b2 = ax.z * inv2, b3 = ax.w * inv3;
            u32 v0 = X[(size_t)src * 80 + t];
            float l0 = bflo(v0), h0 = bfhi(v0);
            yL0 += b0 * l0; yH0 += b0 * h0;
            yL1 += b1 * l0; yH1 += b1 * h0;
            yL2 += b2 * l0; yH2 += b2 * h0;
            yL3 += b3 * l0; yH3 += b3 * h0;
            if (t < 2) {
                u32 e0 = X[(size_t)src * 80 + 64 + t];
                float el0 = bflo(e0), eh0 = bfhi(e0);
                zL0 += b0 * el0; zH0 += b0 * eh0;
                zL1 += b1 * el0; zH1 += b1 * eh0;
                zL2 += b2 * el0; zH2 += b2 * eh0;
                zL3 += b3 * el0; zH3 += b3 * eh0;
            }
        }
    }
    u32* yr = (u32*)(y + (size_t)i * YW);
    yr[t]       = pk2(yL0, yH0);
    yr[68 + t]  = pk2(yL1, yH1);
    yr[136 + t] = pk2(yL2, yH2);
    yr[204 + t] = pk2(yL3, yH3);
    if (t < 2) {
        yr[64 + t]  = pk2(zL0, zH0);
        yr[132 + t] = pk2(zL1, zH1);
        yr[200 + t] = pk2(zL2, zH2);
        yr[268 + t] = pk2(zL3, zH3);
    } else if (t < 4) {
        yr[64 + t] = 0; yr[132 + t] = 0; yr[200 + t] = 0; yr[268 + t] = 0;
    }
}

// ---------------- MLP head ----------------
__global__ __launch_bounds__(256) void k_head(
    const u32* __restrict__ genc, const u16* __restrict__ BTS1,
    const u16* __restrict__ BTS2, const float* __restrict__ b_g1,
    const float* __restrict__ b_g2, float* __restrict__ out) {
    __shared__ u32 g_sm[66];
    __shared__ float h_sm[GFC];
    __shared__ float part[OUT_DIM];
    const int g = blockIdx.x;
    const int tid = threadIdx.x;
    if (tid < 66) {
        float a0 = decf(genc[g * HID + 2 * tid]);
        float a1 = decf(genc[g * HID + 2 * tid + 1]);
        g_sm[tid] = pk2(a0, a1);
    }
    __syncthreads();
    #pragma unroll
    for (int r = 0; r < 4; ++r) {
        int o = tid + 256 * r;
        const u32* wr = (const u32*)(BTS1 + (size_t)o * 160);
        float acc = 0.f;
        for (int c = 0; c < 66; ++c) {
            u32 wv = wr[c], gv = g_sm[c];
            acc += bflo(wv) * bflo(gv) + bfhi(wv) * bfhi(gv);
        }
        acc = fmaxf(acc + b_g1[o], 0.f);
        h_sm[o] = __uint_as_float((u32)f2bf(acc) << 16);
    }
    __syncthreads();
    const int o = tid & 127, half = tid >> 7;
    const u32* wr2 = (const u32*)(BTS2 + (size_t)o * 1024 + half * 512);
    const float* hh = h_sm + half * 512;
    float acc = 0.f;
    for (int c = 0; c < 256; ++c) {
        u32 wv = wr2[c];
        acc += bflo(wv) * hh[2 * c] + bfhi(wv) * hh[2 * c + 1];
    }
    if (half == 1) part[o] = acc;
    __syncthreads();
    if (half == 0) out[(size_t)g * OUT_DIM + o] = acc + part[o] + b_g2[o];
}

// ---------------- launch ----------------
extern "C" void kernel_launch(void* const* d_in, const int* in_sizes, int n_in,
                              void* d_out, int out_size, void* d_ws, size_t ws_size,
                              hipStream_t stream) {
    const float* X       = (const float*)d_in[0];
    const int*   EI      = (const int*)d_in[1];
    const float* EW      = (const float*)d_in[2];
    const float* W_gcn   = (const float*)d_in[4];
    const float* b_gcn   = (const float*)d_in[5];
    const float* W_gat1  = (const float*)d_in[6];
    const float* a_src1  = (const float*)d_in[7];
    const float* a_dst1  = (const float*)d_in[8];
    const float* b_gat1  = (const float*)d_in[9];
    const float* W_gat2  = (const float*)d_in[10];
    const float* a_src2  = (const float*)d_in[11];
    const float* a_dst2  = (const float*)d_in[12];
    const float* b_gat2  = (const float*)d_in[13];
    const float* W_fc1   = (const float*)d_in[14];
    const float* b_fc1   = (const float*)d_in[15];
    const float* W_fc2   = (const float*)d_in[16];
    const float* b_fc2   = (const float*)d_in[17];
    const float* pro_bias= (const float*)d_in[18];
    const float* W_g1    = (const float*)d_in[19];
    const float* b_g1    = (const float*)d_in[20];
    const float* W_g2    = (const float*)d_in[21];
    const float* b_g2    = (const float*)d_in[22];
    float* OUT = (float*)d_out;

    float* ws = (float*)d_ws;
    float*    dis     = ws + O_DIS;
    int*      counts  = (int*)(ws + O_CNT);
    float*    wdeg    = ws + O_WDEG;
    int*      indptr  = (int*)(ws + O_IDP);
    int*      bsum    = (int*)(ws + O_BSUM);
    int*      csr_src = (int*)(ws + O_CSR_S);
    float*    csr_w   = ws + O_CSR_W;
    float*    esd     = ws + O_ESD;
    u32*      genc    = (u32*)(ws + O_GE);
    float*    cmp1    = ws + O_CMP1;
    float*    cmp2    = ws + O_CMP2;
    float*    tmp     = ws + O_TMP;
    u16*      U       = (u16*)(ws + O_U);
    u16*      ABX     = U + U_ABX;
    u16*      AGG     = U + U_AGG;
    u16*      y       = U + U_Y;
    u16*      ABF     = U + U_ABF;
    u16*      ABG     = U + U_ABG;
    u16*      BTG     = U + U_BTG;
    u16*      BTGCN   = U + U_BTGCN;
    u16*      BTY1    = U + U_BTY1;
    u16*      BTY2    = U + U_BTY2;
    u16*      BTS1    = U + U_BTS1;
    u16*      BTS2    = U + U_BTS2;

    const int EB = (N_EDGES + 255) / 256;
    const int NB4 = N_NODES / 4;   // 7500
    const int GB_ = MP / 32;       // 938

    // ---- weight/X conversions + zeroing ----
    k_cvtW<<<(SW_TOT + 255) / 256, 256, 0, stream>>>(
        W_fc1, W_fc2, W_gcn, W_gat1, W_gat2, W_g1, W_g2, X,
        a_src1, a_dst1, a_src2, a_dst2,
        BTG, BTGCN, BTY1, BTY2, BTS1, BTS2, cmp1, cmp2, ABX,
        (u32*)counts, (u32*)wdeg, genc);

    // ---- CSR build ----
    k_count<<<EB, 256, 0, stream>>>(EI, EW, counts, wdeg);
    k_bsum<<<NBLK, 256, 0, stream>>>(counts, wdeg, bsum, dis);
    k_apply<<<NBLK, 256, 0, stream>>>(counts, bsum, indptr);
    k_scatter<<<EB, 256, 0, stream>>>(EI, EW, indptr, counts, csr_src, csr_w);

    // ---- GCN: aggregate X-domain, then GEMM (emits x1 -> ABF/ABG + esd1) ----
    k_gcn_aggX<<<NB4, 256, 0, stream>>>(ABX, indptr, csr_src, csr_w, dis, AGG);
    k_gemm<3, true><<<GB_, 256, 0, stream>>>(AGG, BTGCN, N_NODES, HID, 64,
                                             nullptr, ABF, 160, 160, ABG, 288, 132,
                                             b_gcn, 1, 0, nullptr, nullptr, nullptr,
                                             cmp1, esd);

    // ---- GAT layer 1: gather + fused (projection + gate) ----
    k_gat_node<<<NB4, 256, 0, stream>>>(ABF, esd, indptr, csr_src, tmp, y);
    k_fused<false><<<GB_, 256, 0, stream>>>(y, BTY1, BTG, ABG, ABF,
                                            b_gat1, b_fc1, b_fc2, pro_bias,
                                            cmp2, esd, nullptr, N_NODES);

    // ---- GAT layer 2: gather + fused (projection + gate + pool) ----
    k_gat_node<<<NB4, 256, 0, stream>>>(ABF, esd, indptr, csr_src, tmp, y);
    k_fused<true><<<GB_, 256, 0, stream>>>(y, BTY2, BTG, ABG, nullptr,
                                           b_gat2, b_fc1, b_fc2, pro_bias,
                                           nullptr, nullptr, genc, N_NODES);

    // ---- MLP head ----
    k_head<<<GRAPHS, 256, 0, stream>>>(genc, BTS1, BTS2, b_g1, b_g2, OUT);
}

// Round 17
// 363.113 us; speedup vs baseline: 1.3275x; 1.0008x over previous
//
#include <hip/hip_runtime.h>

// ---------------- problem constants ----------------
constexpr int N_NODES = 30000;
constexpr int N_EDGES = 300000;
constexpr int GRAPHS  = 64;
constexpr int F_IN    = 33;
constexpr int HID     = 132;
constexpr int HID4    = 528;
constexpr int OUT_DIM = 128;
constexpr int GFC     = 1024;
constexpr int MP      = 30016;
constexpr int CAP     = 128;
constexpr int NBLK    = 118;           // ceil(N_NODES/256)
constexpr int YW      = 544;           // y row stride u16
constexpr int A2W     = 296;           // fused-kernel LDS A2 row stride (u16), bank-conflict-free

typedef unsigned int u32;
typedef unsigned short u16;

// ---------------- workspace layout ----------------
constexpr size_t rnd64(size_t x) { return (x + 63) & ~(size_t)63; }
constexpr size_t O_DIS   = 0;
constexpr size_t O_CNT   = O_DIS   + rnd64(N_NODES);
constexpr size_t O_WDEG  = O_CNT   + rnd64(N_NODES);
constexpr size_t O_IDP   = O_WDEG  + rnd64(N_NODES);
constexpr size_t O_BSUM  = O_IDP   + rnd64(N_NODES + 1);
constexpr size_t O_CSR_S = O_BSUM  + rnd64(128);
constexpr size_t O_CSR_W = O_CSR_S + rnd64(N_EDGES);
constexpr size_t O_ESD   = O_CSR_W + rnd64(N_EDGES);                 // float, N*8
constexpr size_t O_GE    = O_ESD   + rnd64((size_t)N_NODES * 8);     // u32, G*HID
constexpr size_t O_CMP1  = O_GE    + rnd64(GRAPHS * HID);            // float, 8*132
constexpr size_t O_CMP2  = O_CMP1  + rnd64(8 * HID);
constexpr size_t O_TMP   = O_CMP2  + rnd64(8 * HID);                 // float, E*4
// u16 region
constexpr size_t O_U     = O_TMP   + rnd64((size_t)N_EDGES * 4);
constexpr size_t U_ABX   = 0;                                        // [MP,64] X bf16
constexpr size_t U_AGG   = U_ABX  + rnd64((size_t)MP * 64);          // [MP,64] aggX
constexpr size_t U_Y     = U_AGG  + rnd64((size_t)MP * 64);          // [MP,YW]
constexpr size_t U_ABF   = U_Y    + rnd64((size_t)MP * YW);          // [MP,160] x table
constexpr size_t U_ABG   = U_ABF  + rnd64((size_t)MP * 160);         // [MP,288]
constexpr size_t U_BTG   = U_ABG  + rnd64((size_t)MP * 288);         // [192,288]
constexpr size_t U_BTGCN = U_BTG  + rnd64(192 * 288);                // [192,64]
constexpr size_t U_BTY1  = U_BTGCN+ rnd64(192 * 64);                 // [192,544]
constexpr size_t U_BTY2  = U_BTY1 + rnd64(192 * 544);                // [192,544]
constexpr size_t U_BTS1  = U_BTY2 + rnd64(192 * 544);                // [1024,160]
constexpr size_t U_BTS2  = U_BTS1 + rnd64(1024 * 160);               // [128,1024]

// ---------------- bf16 helpers ----------------
__device__ inline u16 f2bf(float f) {
    u32 u = __float_as_uint(f);
    return (u16)((u + 0x7fffu + ((u >> 16) & 1u)) >> 16);
}
__device__ inline u32 pk2(float a, float b) { return (u32)f2bf(a) | ((u32)f2bf(b) << 16); }
__device__ inline float bflo(u32 w) { return __uint_as_float(w << 16); }
__device__ inline float bfhi(u32 w) { return __uint_as_float(w & 0xffff0000u); }
__device__ inline float bf1(u16 x) { return __uint_as_float((u32)x << 16); }
__device__ inline u32 encf(float x) {
    u32 u = __float_as_uint(x);
    return (u & 0x80000000u) ? ~u : (u | 0x80000000u);
}
__device__ inline float decf(u32 e) {
    u32 u = (e & 0x80000000u) ? (e & 0x7fffffffu) : ~e;
    return __uint_as_float(u);
}
__device__ inline float fexp(float x) { return __expf(x); }

typedef __attribute__((ext_vector_type(8))) short s8b;
typedef __attribute__((ext_vector_type(4))) float f32x4;

// ---------------- CSR build ----------------
__global__ void k_count(const int* __restrict__ ei, const float* __restrict__ ew,
                        int* __restrict__ counts, float* __restrict__ wdeg) {
    int e = blockIdx.x * 256 + threadIdx.x;
    if (e < N_EDGES) {
        int dst = ei[N_EDGES + e];
        atomicAdd(&counts[dst], 1);
        atomicAdd(&wdeg[dst], ew[e]);
    }
}

__global__ __launch_bounds__(256) void k_bsum(const int* __restrict__ counts,
                                              const float* __restrict__ wdeg,
                                              int* __restrict__ bsum,
                                              float* __restrict__ dis) {
    int i = blockIdx.x * 256 + threadIdx.x;
    int v = (i < N_NODES) ? counts[i] : 0;
    if (i < N_NODES) {
        float d = 1.f + wdeg[i];
        dis[i] = (d > 0.f) ? rsqrtf(fmaxf(d, 1e-12f)) : 0.f;
    }
    int x = v;
    #pragma unroll
    for (int off = 1; off < 64; off <<= 1) x += __shfl_xor(x, off);
    __shared__ int ws4[4];
    if ((threadIdx.x & 63) == 0) ws4[threadIdx.x >> 6] = x;
    __syncthreads();
    if (threadIdx.x == 0) bsum[blockIdx.x] = ws4[0] + ws4[1] + ws4[2] + ws4[3];
}

__global__ __launch_bounds__(256) void k_apply(int* __restrict__ counts,
                                               const int* __restrict__ bsum,
                                               int* __restrict__ indptr) {
    __shared__ int s1[4], s2[4];
    const int b = blockIdx.x;
    const int tid = threadIdx.x, lane = tid & 63, w = tid >> 6;
    int part = (tid < b) ? bsum[tid] : 0;
    #pragma unroll
    for (int off = 1; off < 64; off <<= 1) part += __shfl_xor(part, off);
    if (lane == 0) s1[w] = part;
    int i = b * 256 + tid;
    int v = (i < N_NODES) ? counts[i] : 0;
    int x = v;
    #pragma unroll
    for (int off = 1; off < 64; off <<= 1) {
        int y = __shfl_up(x, off);
        if (lane >= off) x += y;
    }
    if (lane == 63) s2[w] = x;
    __syncthreads();
    int add = s1[0] + s1[1] + s1[2] + s1[3];
    for (int k2 = 0; k2 < w; ++k2) add += s2[k2];
    if (i < N_NODES) {
        indptr[i] = add + x - v;
        counts[i] = 0;
    }
    if (i == N_NODES) indptr[N_NODES] = N_EDGES;
}

__global__ void k_scatter(const int* __restrict__ ei, const float* __restrict__ ew,
                          const int* __restrict__ indptr, int* __restrict__ cursor,
                          int* __restrict__ csr_src, float* __restrict__ csr_w) {
    int e = blockIdx.x * 256 + threadIdx.x;
    if (e >= N_EDGES) return;
    int src = ei[e];
    int dst = ei[N_EDGES + e];
    int pos = indptr[dst] + atomicAdd(&cursor[dst], 1);
    csr_src[pos] = src;
    csr_w[pos] = ew[e];
}

// ---------------- merged weight + X conversion + zeroing ----------------
constexpr int S0 = 192 * 288;
constexpr int S1 = 192 * 64;
constexpr int S2 = 192 * 544;
constexpr int S3 = 192 * 544;
constexpr int S4 = 1024 * 160;
constexpr int S5 = 128 * 1024;
constexpr int S6 = N_NODES * 64;
constexpr int S7 = 2 * 8 * HID;
constexpr int S8 = N_NODES + N_NODES + GRAPHS * HID;
constexpr int SW_TOT = S0 + S1 + S2 + S3 + S4 + S5 + S6 + S7 + S8;

__global__ void k_cvtW(const float* __restrict__ Wfc1, const float* __restrict__ Wfc2,
                       const float* __restrict__ Wgcn, const float* __restrict__ Wgat1,
                       const float* __restrict__ Wgat2, const float* __restrict__ Wg1,
                       const float* __restrict__ Wg2, const float* __restrict__ X,
                       const float* __restrict__ as1, const float* __restrict__ ad1,
                       const float* __restrict__ as2, const float* __restrict__ ad2,
                       u16* __restrict__ BTG, u16* __restrict__ BTGCN,
                       u16* __restrict__ BTY1, u16* __restrict__ BTY2,
                       u16* __restrict__ BTS1, u16* __restrict__ BTS2,
                       float* __restrict__ cmp1, float* __restrict__ cmp2,
                       u16* __restrict__ ABX,
                       u32* __restrict__ zc, u32* __restrict__ zw, u32* __restrict__ zg) {
    int idx = blockIdx.x * 256 + threadIdx.x;
    if (idx < S0) {
        int n = idx / 288, k = idx - n * 288;
        u16 v = 0;
        if (n < HID) {
            if (k < HID) v = f2bf(Wfc1[(size_t)k * HID + n]);
            else if (k < 2 * HID) v = f2bf(Wfc2[(size_t)(k - HID) * HID + n]);
        }
        BTG[idx] = v;
        return;
    }
    idx -= S0;
    if (idx < S1) {
        int n = idx / 64, k = idx - n * 64;
        BTGCN[idx] = (k < F_IN && n < HID) ? f2bf(Wgcn[(size_t)k * HID + n]) : (u16)0;
        return;
    }
    idx -= S1;
    if (idx < S2 + S3) {
        int l = (idx >= S2);
        int li = l ? (idx - S2) : idx;
        int n = li / 544, c = li - n * 544;
        int k = c / 136, j = c - k * 136;
        const float* W = l ? Wgat2 : Wgat1;
        u16 v = 0;
        if (n < HID && j < HID) v = f2bf(0.25f * W[(size_t)j * HID4 + k * HID + n]);
        (l ? BTY2 : BTY1)[li] = v;
        return;
    }
    idx -= S2 + S3;
    if (idx < S4) {
        int n = idx / 160, k = idx - n * 160;
        BTS1[idx] = (k < HID) ? f2bf(Wg1[(size_t)k * GFC + n]) : (u16)0;
        return;
    }
    idx -= S4;
    if (idx < S5) {
        int n = idx / 1024, k = idx - n * 1024;
        BTS2[idx] = f2bf(Wg2[(size_t)k * OUT_DIM + n]);
        return;
    }
    idx -= S5;
    if (idx < S6) {
        int r = idx / 64, k = idx - r * 64;
        ABX[idx] = (k < F_IN) ? f2bf(X[(size_t)r * F_IN + k]) : (u16)0;
        return;
    }
    idx -= S6;
    if (idx < S7) {
        int l = idx / (8 * HID); idx -= l * (8 * HID);
        int q = idx / HID;  int c = idx - q * HID;
        int k = q & 3;
        const float* W = l ? Wgat2 : Wgat1;
        const float* a = (q < 4) ? (l ? as2 : as1) : (l ? ad2 : ad1);
        const float* wr = W + (size_t)c * HID4 + k * HID;
        const float* ar = a + k * HID;
        float sum = 0.f;
        for (int cc = 0; cc < HID; ++cc) sum += wr[cc] * ar[cc];
        (l ? cmp2 : cmp1)[q * HID + c] = sum;
        return;
    }
    idx -= S7;
    if (idx < S8) {
        if (idx < N_NODES) zc[idx] = 0;
        else if (idx < 2 * N_NODES) zw[idx - N_NODES] = 0;
        else zg[idx - 2 * N_NODES] = 0;
    }
}

// ---------------- MFMA bf16 GEMM, M-tile 32 (GCN layer, fused esd) ----------
template <int NT, bool ESD>
__global__ __launch_bounds__(256) void k_gemm(
    const u16* __restrict__ A, const u16* __restrict__ Bt,
    int M, int N, int Kp,
    float* __restrict__ Cf,
    u16* __restrict__ Cb, int ldcb, int padN,
    u16* __restrict__ Cb2, int ldcb2, int coff2,
    const float* __restrict__ bias, int relu, int gate,
    const float* __restrict__ b2, const float* __restrict__ pb,
    u32* __restrict__ genc,
    const float* __restrict__ compG, float* __restrict__ esdOut) {
    __shared__ float xs[ESD ? 32 : 1][134];
    __shared__ float cmp[ESD ? 8 : 1][132];
    const int bm = blockIdx.x * 32;
    const int w = threadIdx.x >> 6;
    const int lane = threadIdx.x & 63;
    const int m16 = lane & 15;
    const int quad = lane >> 4;
    const u16* Ab = A + (size_t)(bm + m16) * Kp + quad * 8;
    const u16* Bb[NT];
    #pragma unroll
    for (int j = 0; j < NT; ++j)
        Bb[j] = Bt + (size_t)(j * 64 + w * 16 + m16) * Kp + quad * 8;
    f32x4 acc[NT][2];
    #pragma unroll
    for (int j = 0; j < NT; ++j)
        #pragma unroll
        for (int r = 0; r < 2; ++r) acc[j][r] = (f32x4){0.f, 0.f, 0.f, 0.f};
    for (int k0 = 0; k0 < Kp; k0 += 32) {
        s8b a0 = *(const s8b*)(Ab + k0);
        s8b a1 = *(const s8b*)(Ab + (size_t)16 * Kp + k0);
        #pragma unroll
        for (int j = 0; j < NT; ++j) {
            s8b b = *(const s8b*)(Bb[j] + k0);
            acc[j][0] = __builtin_amdgcn_mfma_f32_16x16x32_bf16(a0, b, acc[j][0], 0, 0, 0);
            acc[j][1] = __builtin_amdgcn_mfma_f32_16x16x32_bf16(a1, b, acc[j][1], 0, 0, 0);
        }
    }
    const int g0 = (bm * GRAPHS) / N_NODES;
    int gend = bm + 31; if (gend >= M) gend = M - 1;
    const int g1 = (gend * GRAPHS) / N_NODES;
    #pragma unroll
    for (int j = 0; j < NT; ++j) {
        const int col = j * 64 + w * 16 + m16;
        const bool colok = col < N;
        float bsum = 0.f;
        if (colok) {
            if (gate) bsum = bias[col] + b2[col] + pb[col];
            else if (bias) bsum = bias[col];
        }
        float mx0 = -3.4e38f, mx1 = -3.4e38f;
        #pragma unroll
        for (int r = 0; r < 2; ++r) {
            #pragma unroll
            for (int jj = 0; jj < 4; ++jj) {
                int row = bm + r * 16 + quad * 4 + jj;
                if (row >= M || !colok) continue;
                float v = acc[j][r][jj] + bsum;
                float res;
                if (gate) {
                    float z = 1.f / (1.f + fexp(-v));
                    float xcv = bf1(A[(size_t)row * Kp + col]);
                    float xpv = bf1(A[(size_t)row * Kp + 132 + col]);
                    res = z * xcv + (1.f - z) * xpv;
                } else {
                    if (relu) v = fmaxf(v, 0.f);
                    res = v;
                }
                if constexpr (ESD) {
                    if (col < 132) xs[row - bm][col] = res;
                }
                if (genc) {
                    int gid = (row * GRAPHS) / N_NODES;
                    if (gid == g0) mx0 = fmaxf(mx0, res);
                    else           mx1 = fmaxf(mx1, res);
                }
                if (Cf) Cf[(size_t)row * N + col] = res;
                if (Cb) Cb[(size_t)row * ldcb + col] = f2bf(res);
                if (Cb2) Cb2[(size_t)row * ldcb2 + coff2 + col] = f2bf(res);
            }
        }
        if (genc && colok) {
            mx0 = fmaxf(mx0, __shfl_xor(mx0, 16));
            mx0 = fmaxf(mx0, __shfl_xor(mx0, 32));
            if (g1 != g0) {
                mx1 = fmaxf(mx1, __shfl_xor(mx1, 16));
                mx1 = fmaxf(mx1, __shfl_xor(mx1, 32));
            }
            if (quad == 0) {
                atomicMax(&genc[g0 * HID + col], encf(mx0));
                if (g1 != g0) atomicMax(&genc[g1 * HID + col], encf(mx1));
            }
        }
    }
    if constexpr (ESD) {
        for (int i2 = threadIdx.x; i2 < 8 * HID; i2 += 256)
            cmp[i2 / HID][i2 % HID] = compG[i2];
        __syncthreads();
        int row = threadIdx.x >> 3, q8 = threadIdx.x & 7;
        if (bm + row < M) {
            float s = 0.f;
            for (int c = 0; c < HID; ++c) s += xs[row][c] * cmp[q8][c];
            esdOut[(size_t)(bm + row) * 8 + q8] = s;
        }
    }
}

// ---------------- fused GAT-projection + gate kernel (two-stage MFMA) --------
template <bool L2>
__global__ __launch_bounds__(256) void k_fused(
    const u16* __restrict__ yv, const u16* __restrict__ BTY,
    const u16* __restrict__ BTGm, u16* __restrict__ ABG,
    u16* __restrict__ ABF,
    const float* __restrict__ bgat,
    const float* __restrict__ bfc1, const float* __restrict__ bfc2,
    const float* __restrict__ pb,
    const float* __restrict__ compG, float* __restrict__ esdOut,
    u32* __restrict__ genc, int M) {
    __shared__ u16 a2[32 * A2W];
    __shared__ float xs[L2 ? 1 : 32][134];
    __shared__ float cmp[L2 ? 1 : 8][132];
    const int bm = blockIdx.x * 32;
    const int w = threadIdx.x >> 6;
    const int lane = threadIdx.x & 63;
    const int m16 = lane & 15;
    const int quad = lane >> 4;
    // xp + pad into A2 cols 132..295 (u32 cols 66..147)
    u32* a2u = (u32*)a2;
    for (int idx = threadIdx.x; idx < 32 * 82; idx += 256) {
        int row = idx / 82, c = idx - row * 82;
        u32 v = 0;
        if (c < 66 && bm + row < M)
            v = ((const u32*)ABG)[(size_t)(bm + row) * 144 + 66 + c];
        a2u[row * (A2W / 2) + 66 + c] = v;
    }
    // ---- stage A ----
    const u16* Ab = yv + (size_t)(bm + m16) * YW + quad * 8;
    const u16* Bb[3];
    #pragma unroll
    for (int j = 0; j < 3; ++j)
        Bb[j] = BTY + (size_t)(j * 64 + w * 16 + m16) * YW + quad * 8;
    f32x4 acc1[3][2];
    #pragma unroll
    for (int j = 0; j < 3; ++j)
        #pragma unroll
        for (int r = 0; r < 2; ++r) acc1[j][r] = (f32x4){0.f, 0.f, 0.f, 0.f};
    for (int k0 = 0; k0 < YW; k0 += 32) {
        s8b a0 = *(const s8b*)(Ab + k0);
        s8b a1 = *(const s8b*)(Ab + (size_t)16 * YW + k0);
        #pragma unroll
        for (int j = 0; j < 3; ++j) {
            s8b b = *(const s8b*)(Bb[j] + k0);
            acc1[j][0] = __builtin_amdgcn_mfma_f32_16x16x32_bf16(a0, b, acc1[j][0], 0, 0, 0);
            acc1[j][1] = __builtin_amdgcn_mfma_f32_16x16x32_bf16(a1, b, acc1[j][1], 0, 0, 0);
        }
    }
    #pragma unroll
    for (int j = 0; j < 3; ++j) {
        const int col = j * 64 + w * 16 + m16;
        if (col >= HID) continue;
        const float bc = bgat[col];
        #pragma unroll
        for (int r = 0; r < 2; ++r) {
            #pragma unroll
            for (int jj = 0; jj < 4; ++jj) {
                int row = bm + r * 16 + quad * 4 + jj;
                float v = acc1[j][r][jj] + bc;
                if (!L2) v = fmaxf(v, 0.f);
                acc1[j][r][jj] = v;
                if (row < M) a2[(row - bm) * A2W + col] = f2bf(v);
            }
        }
    }
    __syncthreads();
    // ---- stage B ----
    const u16* A2b = a2 + m16 * A2W + quad * 8;
    const u16* Bg[3];
    #pragma unroll
    for (int j = 0; j < 3; ++j)
        Bg[j] = BTGm + (size_t)(j * 64 + w * 16 + m16) * 288 + quad * 8;
    f32x4 acc2[3][2];
    #pragma unroll
    for (int j = 0; j < 3; ++j)
        #pragma unroll
        for (int r = 0; r < 2; ++r) acc2[j][r] = (f32x4){0.f, 0.f, 0.f, 0.f};
    for (int k0 = 0; k0 < 288; k0 += 32) {
        s8b a0 = *(const s8b*)(A2b + k0);
        s8b a1 = *(const s8b*)(A2b + 16 * A2W + k0);
        #pragma unroll
        for (int j = 0; j < 3; ++j) {
            s8b b = *(const s8b*)(Bg[j] + k0);
            acc2[j][0] = __builtin_amdgcn_mfma_f32_16x16x32_bf16(a0, b, acc2[j][0], 0, 0, 0);
            acc2[j][1] = __builtin_amdgcn_mfma_f32_16x16x32_bf16(a1, b, acc2[j][1], 0, 0, 0);
        }
    }
    const int g0 = (bm * GRAPHS) / N_NODES;
    int gend = bm + 31; if (gend >= M) gend = M - 1;
    const int g1 = (gend * GRAPHS) / N_NODES;
    #pragma unroll
    for (int j = 0; j < 3; ++j) {
        const int col = j * 64 + w * 16 + m16;
        const bool colok = col < HID;
        float bsum = colok ? (bfc1[col] + bfc2[col] + pb[col]) : 0.f;
        float mx0 = -3.4e38f, mx1 = -3.4e38f;
        #pragma unroll
        for (int r = 0; r < 2; ++r) {
            #pragma unroll
            for (int jj = 0; jj < 4; ++jj) {
                int row = bm + r * 16 + quad * 4 + jj;
                if (row >= M || !colok) continue;
                float pre = acc2[j][r][jj] + bsum;
                float z = 1.f / (1.f + fexp(-pre));
                float xcv = acc1[j][r][jj];
                float xpv = bf1(a2[(row - bm) * A2W + 132 + col]);
                float res = z * xcv + (1.f - z) * xpv;
                if (!L2) {
                    ABF[(size_t)row * 160 + col] = f2bf(res);
                    ABG[(size_t)row * 288 + 132 + col] = f2bf(res);
                    xs[row - bm][col] = res;
                } else {
                    int gid = (row * GRAPHS) / N_NODES;
                    if (gid == g0) mx0 = fmaxf(mx0, res);
                    else           mx1 = fmaxf(mx1, res);
                }
            }
        }
        if (L2 && colok) {
            mx0 = fmaxf(mx0, __shfl_xor(mx0, 16));
            mx0 = fmaxf(mx0, __shfl_xor(mx0, 32));
            if (g1 != g0) {
                mx1 = fmaxf(mx1, __shfl_xor(mx1, 16));
                mx1 = fmaxf(mx1, __shfl_xor(mx1, 32));
            }
            if (quad == 0) {
                atomicMax(&genc[g0 * HID + col], encf(mx0));
                if (g1 != g0) atomicMax(&genc[g1 * HID + col], encf(mx1));
            }
        }
    }
    if constexpr (!L2) {
        for (int i2 = threadIdx.x; i2 < 8 * HID; i2 += 256)
            cmp[i2 / HID][i2 % HID] = compG[i2];
        __syncthreads();
        int row = threadIdx.x >> 3, q8 = threadIdx.x & 7;
        if (bm + row < M) {
            float s = 0.f;
            for (int c = 0; c < HID; ++c) s += xs[row][c] * cmp[q8][c];
            esdOut[(size_t)(bm + row) * 8 + q8] = s;
        }
    }
}

// ---------------- GCN aggregate in X-domain (33 ch, 2 edges/wave-iter) -------
__global__ __launch_bounds__(256) void k_gcn_aggX(
    const u16* __restrict__ xb, const int* __restrict__ indptr,
    const int* __restrict__ csr_src, const float* __restrict__ csr_w,
    const float* __restrict__ dis, u16* __restrict__ aggx) {
    const int w = threadIdx.x >> 6, t = threadIdx.x & 63;
    const int i = blockIdx.x * 4 + w;
    const int g = t >> 5;
    const int c = t & 31;
    const float di = dis[i];
    const int s = indptr[i], e = indptr[i + 1];
    const u32* X32 = (const u32*)xb;
    float aLo = 0.f, aHi = 0.f;
    int j = s;
    for (; j + 3 < e; j += 4) {
        int j0 = j + g, j1 = j + 2 + g;
        int s0 = csr_src[j0], s1 = csr_src[j1];
        float n0 = dis[s0] * csr_w[j0] * di;
        float n1 = dis[s1] * csr_w[j1] * di;
        u32 v0 = X32[(size_t)s0 * 32 + c];
        u32 v1 = X32[(size_t)s1 * 32 + c];
        aLo += n0 * bflo(v0) + n1 * bflo(v1);
        aHi += n0 * bfhi(v0) + n1 * bfhi(v1);
    }
    for (; j < e; j += 2) {
        int jj = j + g;
        if (jj < e) {
            int s0 = csr_src[jj];
            float n0 = dis[s0] * csr_w[jj] * di;
            u32 v0 = X32[(size_t)s0 * 32 + c];
            aLo += n0 * bflo(v0);
            aHi += n0 * bfhi(v0);
        }
    }
    aLo += __shfl_xor(aLo, 32);
    aHi += __shfl_xor(aHi, 32);
    if (t < 32) {
        float nself = di * di;
        u32 v = X32[(size_t)i * 32 + t];
        aLo += nself * bflo(v);
        aHi += nself * bfhi(v);
        ((u32*)aggx)[(size_t)i * 32 + t] = pk2(aLo, aHi);
    }
}

// ---------------- GAT softmax (no-max, distributed exp) + x-domain aggregate -
__global__ __launch_bounds__(256) void k_gat_node(
    const u16* __restrict__ xt, const float* __restrict__ esd,
    const int* __restrict__ indptr, const int* __restrict__ csr_src,
    float* __restrict__ tmp, u16* __restrict__ y) {
    __shared__ __align__(16) float al[4][CAP * 4];
    __shared__ int srcl[4][CAP];
    const int w = threadIdx.x >> 6, t = threadIdx.x & 63;
    const int i = blockIdx.x * 4 + w;
    const int k = t & 3;
    const int s = indptr[i];
    const int deg = indptr[i + 1] - s;
    const bool fast = (deg <= CAP);
    const float edk = esd[i * 8 + 4 + k];
    float eself = esd[i * 8 + k] + edk;
    eself = (eself >= 0.f) ? eself : 0.2f * eself;
    float dsum = 0.f;
    for (int j0 = 0; j0 < deg; j0 += 16) {
        int j = j0 + (t >> 2);
        if (j < deg) {
            int src = csr_src[s + j];
            float e = esd[src * 8 + k] + edk;
            e = (e >= 0.f) ? e : 0.2f * e;
            float ex = fexp(e);
            if (fast) { al[w][j * 4 + k] = ex; if (k == 0) srcl[w][j] = src; }
            else tmp[(size_t)(s + j) * 4 + k] = ex;
            dsum += ex;
        }
    }
    dsum += __shfl_xor(dsum, 4);
    dsum += __shfl_xor(dsum, 8);
    dsum += __shfl_xor(dsum, 16);
    dsum += __shfl_xor(dsum, 32);
    float exs = fexp(eself);
    dsum += exs;
    float inv = 1.f / dsum;
    float aself = exs * inv;
    float a0 = __shfl(aself, 0), a1 = __shfl(aself, 1);
    float a2 = __shfl(aself, 2), a3 = __shfl(aself, 3);
    if (fast) {
        for (int idx = t; idx < deg * 4; idx += 64) al[w][idx] *= inv;
    }
    const u32* X = (const u32*)xt;   // row stride 80 u32
    float yL0, yH0, yL1, yH1, yL2, yH2, yL3, yH3;
    float zL0 = 0, zH0 = 0, zL1 = 0, zH1 = 0, zL2 = 0, zH2 = 0, zL3 = 0, zH3 = 0;
    {
        u32 v = X[(size_t)i * 80 + t];
        float lo = bflo(v), hi = bfhi(v);
        yL0 = a0 * lo; yH0 = a0 * hi;
        yL1 = a1 * lo; yH1 = a1 * hi;
        yL2 = a2 * lo; yH2 = a2 * hi;
        yL3 = a3 * lo; yH3 = a3 * hi;
        if (t < 2) {
            u32 v2 = X[(size_t)i * 80 + 64 + t];
            float l2 = bflo(v2), h2 = bfhi(v2);
            zL0 = a0 * l2; zH0 = a0 * h2;
            zL1 = a1 * l2; zH1 = a1 * h2;
            zL2 = a2 * l2; zH2 = a2 * h2;
            zL3 = a3 * l2; zH3 = a3 * h2;
        }
    }
    if (fast) {
        int j = 0;
        for (; j + 3 < deg; j += 4) {
            int s0 = srcl[w][j], s1 = srcl[w][j + 1], s2 = srcl[w][j + 2], s3 = srcl[w][j + 3];
            u32 v0 = X[(size_t)s0 * 80 + t];
            u32 v1 = X[(size_t)s1 * 80 + t];
            u32 v2 = X[(size_t)s2 * 80 + t];
            u32 v3 = X[(size_t)s3 * 80 + t];
            float4 x0 = *(const float4*)&al[w][j * 4];
            float4 x1 = *(const float4*)&al[w][j * 4 + 4];
            float4 x2 = *(const float4*)&al[w][j * 4 + 8];
            float4 x3 = *(const float4*)&al[w][j * 4 + 12];
            float l0 = bflo(v0), h0 = bfhi(v0), l1 = bflo(v1), h1 = bfhi(v1);
            float l2 = bflo(v2), h2 = bfhi(v2), l3 = bflo(v3), h3 = bfhi(v3);
            yL0 += x0.x * l0 + x1.x * l1 + x2.x * l2 + x3.x * l3;
            yH0 += x0.x * h0 + x1.x * h1 + x2.x * h2 + x3.x * h3;
            yL1 += x0.y * l0 + x1.y * l1 + x2.y * l2 + x3.y * l3;
            yH1 += x0.y * h0 + x1.y * h1 + x2.y * h2 + x3.y * h3;
            yL2 += x0.z * l0 + x1.z * l1 + x2.z * l2 + x3.z * l3;
            yH2 += x0.z * h0 + x1.z * h1 + x2.z * h2 + x3.z * h3;
            yL3 += x0.w * l0 + x1.w * l1 + x2.w * l2 + x3.w * l3;
            yH3 += x0.w * h0 + x1.w * h1 + x2.w * h2 + x3.w * h3;
            if (t < 2) {
                u32 e0 = X[(size_t)s0 * 80 + 64 + t];
                u32 e1 = X[(size_t)s1 * 80 + 64 + t];
                u32 e2 = X[(size_t)s2 * 80 + 64 + t];
                u32 e3 = X[(size_t)s3 * 80 + 64 + t];
                float el0 = bflo(e0), eh0 = bfhi(e0), el1 = bflo(e1), eh1 = bfhi(e1);
                float el2 = bflo(e2), eh2 = bfhi(e2), el3 = bflo(e3), eh3 = bfhi(e3);
                zL0 += x0.x * el0 + x1.x * el1 + x2.x * el2 + x3.x * el3;
                zH0 += x0.x * eh0 + x1.x * eh1 + x2.x * eh2 + x3.x * eh3;
                zL1 += x0.y * el0 + x1.y * el1 + x2.y * el2 + x3.y * el3;
                zH1 += x0.y * eh0 + x1.y * eh1 + x2.y * eh2 + x3.y * eh3;
                zL2 += x0.z * el0 + x1.z * el1 + x2.z * el2 + x3.z * el3;
                zH2 += x0.z * eh0 + x1.z * eh1 + x2.z * eh2 + x3.z * eh3;
                zL3 += x0.w * el0 + x1.w * el1 + x2.w * el2 + x3.w * el3;
                zH3 += x0.w * eh0 + x1.w * eh1 + x2.w * eh2 + x3.w * eh3;
            }
        }
        for (; j < deg; ++j) {
            int s0 = srcl[w][j];
            u32 v0 = X[(size_t)s0 * 80 + t];
            float4 x0 = *(const float4*)&al[w][j * 4];
            float l0 = bflo(v0), h0 = bfhi(v0);
            yL0 += x0.x * l0; yH0 += x0.x * h0;
            yL1 += x0.y * l0; yH1 += x0.y * h0;
            yL2 += x0.z * l0; yH2 += x0.z * h0;
            yL3 += x0.w * l0; yH3 += x0.w * h0;
            if (t < 2) {
                u32 e0 = X[(size_t)s0 * 80 + 64 + t];
                float el0 = bflo(e0), eh0 = bfhi(e0);
                zL0 += x0.x * el0; zH0 += x0.x * eh0;
                zL1 += x0.y * el0; zH1 += x0.y * eh0;
                zL2 += x0.z * el0; zH2 += x0.z * eh0;
                zL3 += x0.w * el0; zH3 += x0.w * eh0;
            }
        }
    } else {
        float inv0 = __shfl(inv, 0), inv1 = __shfl(inv, 1);
        float inv2 = __shfl(inv, 2), inv3 = __shfl(inv, 3);
        const float4* tmp4 = (const float4*)tmp;
        for (int j = 0; j < deg; ++j) {
            int src = csr_src[s + j];
            float4 ax = tmp4[s + j];
            float b0 = ax.x * inv0, b1 = ax.y * inv1, b2 = ax.z * inv2, b3 = ax.w * inv3;
            u32 v0 = X[(size_t)src * 80 + t];
            float l0 = bflo(v0), h0 = bfhi(v0);
            yL0 += b0 * l0; yH0 += b0 * h0;
            yL1 += b1 * l0; yH1 += b1 * h0;
            yL2 += b2 * l0; yH2 += b2 * h0;
            yL3 += b3 * l0; yH3 += b3 * h0;
            if (t < 2) {
                u32 e0 = X[(size_t)src * 80 + 64 + t];
                float el0 = bflo(e0), eh0 = bfhi(e0);
                zL0 += b0 * el0; zH0 += b0 * eh0;
                zL1 += b1 * el0; zH1 += b1 * eh0;
                zL2 += b2 * el0; zH2 += b2 * eh0;
                zL3 += b3 * el0; zH3 += b3 * eh0;
            }
        }
    }
    u32* yr = (u32*)(y + (size_t)i * YW);
    yr[t]       = pk2(yL0, yH0);
    yr[68 + t]  = pk2(yL1, yH1);
    yr[136 + t] = pk2(yL2, yH2);
    yr[204 + t] = pk2(yL3, yH3);
    if (t < 2) {
        yr[64 + t]  = pk2(zL0, zH0);
        yr[132 + t] = pk2(zL1, zH1);
        yr[200 + t] = pk2(zL2, zH2);
        yr[268 + t] = pk2(zL3, zH3);
    } else if (t < 4) {
        yr[64 + t] = 0; yr[132 + t] = 0; yr[200 + t] = 0; yr[268 + t] = 0;
    }
}

// ---------------- MLP head ----------------
__global__ __launch_bounds__(256) void k_head(
    const u32* __restrict__ genc, const u16* __restrict__ BTS1,
    const u16* __restrict__ BTS2, const float* __restrict__ b_g1,
    const float* __restrict__ b_g2, float* __restrict__ out) {
    __shared__ u32 g_sm[66];
    __shared__ float h_sm[GFC];
    __shared__ float part[OUT_DIM];
    const int g = blockIdx.x;
    const int tid = threadIdx.x;
    if (tid < 66) {
        float a0 = decf(genc[g * HID + 2 * tid]);
        float a1 = decf(genc[g * HID + 2 * tid + 1]);
        g_sm[tid] = pk2(a0, a1);
    }
    __syncthreads();
    #pragma unroll
    for (int r = 0; r < 4; ++r) {
        int o = tid + 256 * r;
        const u32* wr = (const u32*)(BTS1 + (size_t)o * 160);
        float acc = 0.f;
        for (int c = 0; c < 66; ++c) {
            u32 wv = wr[c], gv = g_sm[c];
            acc += bflo(wv) * bflo(gv) + bfhi(wv) * bfhi(gv);
        }
        acc = fmaxf(acc + b_g1[o], 0.f);
        h_sm[o] = __uint_as_float((u32)f2bf(acc) << 16);
    }
    __syncthreads();
    const int o = tid & 127, half = tid >> 7;
    const u32* wr2 = (const u32*)(BTS2 + (size_t)o * 1024 + half * 512);
    const float* hh = h_sm + half * 512;
    float acc = 0.f;
    for (int c = 0; c < 256; ++c) {
        u32 wv = wr2[c];
        acc += bflo(wv) * hh[2 * c] + bfhi(wv) * hh[2 * c + 1];
    }
    if (half == 1) part[o] = acc;
    __syncthreads();
    if (half == 0) out[(size_t)g * OUT_DIM + o] = acc + part[o] + b_g2[o];
}

// ---------------- launch ----------------
extern "C" void kernel_launch(void* const* d_in, const int* in_sizes, int n_in,
                              void* d_out, int out_size, void* d_ws, size_t ws_size,
                              hipStream_t stream) {
    const float* X       = (const float*)d_in[0];
    const int*   EI      = (const int*)d_in[1];
    const float* EW      = (const float*)d_in[2];
    const float* W_gcn   = (const float*)d_in[4];
    const float* b_gcn   = (const float*)d_in[5];
    const float* W_gat1  = (const float*)d_in[6];
    const float* a_src1  = (const float*)d_in[7];
    const float* a_dst1  = (const float*)d_in[8];
    const float* b_gat1  = (const float*)d_in[9];
    const float* W_gat2  = (const float*)d_in[10];
    const float* a_src2  = (const float*)d_in[11];
    const float* a_dst2  = (const float*)d_in[12];
    const float* b_gat2  = (const float*)d_in[13];
    const float* W_fc1   = (const float*)d_in[14];
    const float* b_fc1   = (const float*)d_in[15];
    const float* W_fc2   = (const float*)d_in[16];
    const float* b_fc2   = (const float*)d_in[17];
    const float* pro_bias= (const float*)d_in[18];
    const float* W_g1    = (const float*)d_in[19];
    const float* b_g1    = (const float*)d_in[20];
    const float* W_g2    = (const float*)d_in[21];
    const float* b_g2    = (const float*)d_in[22];
    float* OUT = (float*)d_out;

    float* ws = (float*)d_ws;
    float*    dis     = ws + O_DIS;
    int*      counts  = (int*)(ws + O_CNT);
    float*    wdeg    = ws + O_WDEG;
    int*      indptr  = (int*)(ws + O_IDP);
    int*      bsum    = (int*)(ws + O_BSUM);
    int*      csr_src = (int*)(ws + O_CSR_S);
    float*    csr_w   = ws + O_CSR_W;
    float*    esd     = ws + O_ESD;
    u32*      genc    = (u32*)(ws + O_GE);
    float*    cmp1    = ws + O_CMP1;
    float*    cmp2    = ws + O_CMP2;
    float*    tmp     = ws + O_TMP;
    u16*      U       = (u16*)(ws + O_U);
    u16*      ABX     = U + U_ABX;
    u16*      AGG     = U + U_AGG;
    u16*      y       = U + U_Y;
    u16*      ABF     = U + U_ABF;
    u16*      ABG     = U + U_ABG;
    u16*      BTG     = U + U_BTG;
    u16*      BTGCN   = U + U_BTGCN;
    u16*      BTY1    = U + U_BTY1;
    u16*      BTY2    = U + U_BTY2;
    u16*      BTS1    = U + U_BTS1;
    u16*      BTS2    = U + U_BTS2;

    const int EB = (N_EDGES + 255) / 256;
    const int NB4 = N_NODES / 4;   // 7500
    const int GB_ = MP / 32;       // 938

    // ---- weight/X conversions + zeroing ----
    k_cvtW<<<(SW_TOT + 255) / 256, 256, 0, stream>>>(
        W_fc1, W_fc2, W_gcn, W_gat1, W_gat2, W_g1, W_g2, X,
        a_src1, a_dst1, a_src2, a_dst2,
        BTG, BTGCN, BTY1, BTY2, BTS1, BTS2, cmp1, cmp2, ABX,
        (u32*)counts, (u32*)wdeg, genc);

    // ---- CSR build ----
    k_count<<<EB, 256, 0, stream>>>(EI, EW, counts, wdeg);
    k_bsum<<<NBLK, 256, 0, stream>>>(counts, wdeg, bsum, dis);
    k_apply<<<NBLK, 256, 0, stream>>>(counts, bsum, indptr);
    k_scatter<<<EB, 256, 0, stream>>>(EI, EW, indptr, counts, csr_src, csr_w);

    // ---- GCN: aggregate X-domain, then GEMM (emits x1 -> ABF/ABG + esd1) ----
    k_gcn_aggX<<<NB4, 256, 0, stream>>>(ABX, indptr, csr_src, csr_w, dis, AGG);
    k_gemm<3, true><<<GB_, 256, 0, stream>>>(AGG, BTGCN, N_NODES, HID, 64,
                                             nullptr, ABF, 160, 160, ABG, 288, 132,
                                             b_gcn, 1, 0, nullptr, nullptr, nullptr,
                                             cmp1, esd);

    // ---- GAT layer 1: gather + fused (projection + gate) ----
    k_gat_node<<<NB4, 256, 0, stream>>>(ABF, esd, indptr, csr_src, tmp, y);
    k_fused<false><<<GB_, 256, 0, stream>>>(y, BTY1, BTG, ABG, ABF,
                                            b_gat1, b_fc1, b_fc2, pro_bias,
                                            cmp2, esd, nullptr, N_NODES);

    // ---- GAT layer 2: gather + fused (projection + gate + pool) ----
    k_gat_node<<<NB4, 256, 0, stream>>>(ABF, esd, indptr, csr_src, tmp, y);
    k_fused<true><<<GB_, 256, 0, stream>>>(y, BTY2, BTG, ABG, nullptr,
                                           b_gat2, b_fc1, b_fc2, pro_bias,
                                           nullptr, nullptr, genc, N_NODES);

    // ---- MLP head ----
    k_head<<<GRAPHS, 256, 0, stream>>>(genc, BTS1, BTS2, b_g1, b_g2, OUT);
}